// Round 2
// baseline (984.389 us; speedup 1.0000x reference)
//
#include <hip/hip_runtime.h>
#include <hip/hip_bf16.h>

// Problem constants (reference: B=4, T=2048, D=256, H=4, DK=64, P=2T-1)
#define Bc 4
#define Tc 2048
#define Dc 256
#define Hc 4
#define DKc 64
#define Pc 4095

// ---------------------------------------------------------------------------
// Generic projection GEMM: out = A @ W^T (+ bias) (+ add), A is M x 256,
// W is 256 x 256 row-major (N x K). Optional head-split output layout
// (b,h,t,dk) used for q/k/v/p so the attention kernel gets contiguous rows.
// 64x64 block tile, BK=16, 256 threads, 4x4 microtile. LDS stride 68 floats.
// ---------------------------------------------------------------------------
__global__ __launch_bounds__(256) void gemm_proj(
    const float* __restrict__ A,
    const float* __restrict__ Wt,
    const float* __restrict__ bias,   // nullable
    const float* __restrict__ addv,   // nullable (pos_bias_u for the q proj)
    float* __restrict__ out,
    int M, int Tdim, int headsplit)
{
    __shared__ float As[16][68];
    __shared__ float Bs[16][68];
    const int tid = threadIdx.x;
    const int tx = tid & 15, ty = tid >> 4;
    const int m0 = blockIdx.x * 64, n0 = blockIdx.y * 64;

    float acc[4][4] = {};

    for (int k0 = 0; k0 < 256; k0 += 16) {
        #pragma unroll
        for (int r = 0; r < 4; r++) {
            int lin = tid + r * 256;          // 0..1023
            int mm = lin >> 4, kk = lin & 15; // consecutive tid -> consecutive k (coalesced 64B)
            int gm = m0 + mm;
            As[kk][mm] = (gm < M) ? A[(size_t)gm * 256 + k0 + kk] : 0.f;
            Bs[kk][mm] = Wt[(size_t)(n0 + mm) * 256 + k0 + kk];
        }
        __syncthreads();
        #pragma unroll
        for (int k = 0; k < 16; k++) {
            float4 a4 = *(const float4*)&As[k][ty * 4];
            float4 b4 = *(const float4*)&Bs[k][tx * 4];
            float av[4] = {a4.x, a4.y, a4.z, a4.w};
            float bv[4] = {b4.x, b4.y, b4.z, b4.w};
            #pragma unroll
            for (int i = 0; i < 4; i++)
                #pragma unroll
                for (int j = 0; j < 4; j++)
                    acc[i][j] = fmaf(av[i], bv[j], acc[i][j]);
        }
        __syncthreads();
    }

    #pragma unroll
    for (int i = 0; i < 4; i++) {
        int gm = m0 + ty * 4 + i;
        if (gm >= M) continue;
        float vrow[4];
        #pragma unroll
        for (int j = 0; j < 4; j++) {
            int gn = n0 + tx * 4 + j;
            float v = acc[i][j];
            if (bias) v += bias[gn];
            if (addv) v += addv[gn];
            vrow[j] = v;
        }
        int gn0 = n0 + tx * 4;
        size_t oidx;
        if (headsplit) {
            int bb = gm / Tdim, t = gm % Tdim;
            int hh = gn0 >> 6, dk = gn0 & 63;  // BN=64 == DK, so 4 cols stay in one head
            oidx = ((size_t)(bb * Hc + hh) * Tdim + t) * DKc + dk;
        } else {
            oidx = (size_t)gm * 256 + gn0;
        }
        *(float4*)&out[oidx] = make_float4(vrow[0], vrow[1], vrow[2], vrow[3]);
    }
}

// ---------------------------------------------------------------------------
// dpw[h][w] = (pos_bias_v - pos_bias_u)[h] . p[h][w][:]   (H x P, ~16K dots)
// ---------------------------------------------------------------------------
__global__ __launch_bounds__(256) void dpw_kernel(
    const float* __restrict__ ph,    // (H,P,DK)
    const float* __restrict__ pbu,
    const float* __restrict__ pbv,
    float* __restrict__ dpw)         // (H,P)
{
    int idx = blockIdx.x * 256 + threadIdx.x;   // h*P + w
    if (idx >= Hc * Pc) return;
    int h = idx / Pc;
    const float* row = ph + (size_t)idx * DKc;
    const float* u = pbu + h * DKc;
    const float* v = pbv + h * DKc;
    float acc = 0.f;
    #pragma unroll
    for (int d = 0; d < DKc; d++)
        acc = fmaf(v[d] - u[d], row[d], acc);
    dpw[idx] = acc;
}

// ---------------------------------------------------------------------------
// Flash-style relative-position attention.
//   scores[t,j] = ( qu[t]·k[j] + qu[t]·p[w] + dpw[w] ) / 8 + maskadd[j]
// with w = j - t + T-1 (rel_shift band), dpw precomputed.
// QT=KT=64, 256 threads, 4x4 microtile, online softmax, O accum in regs.
// LDS layout for Q/K/V/P tiles: unpadded stride 16 float4 with XOR swizzle
//   c4' = c4 ^ ((row>>2)&7)
// so row-strided ds_read_b128 (rows 4*tx apart) spread over 8 bank groups
// (2-way = free) instead of 2 groups (8-way = 2.94x). ~98 KB LDS -> 1 blk/CU.
// ---------------------------------------------------------------------------
#define QT 64
#define KT 64
#define WIN 127   // KT + QT - 1

// float4-granular swizzled index; multiply by 4 for float index
#define SW(row, c4) ((((row) << 4) | ((c4) ^ (((row) >> 2) & 7))))

__device__ __forceinline__ void f4arr(float4 v, float* a) {
    a[0] = v.x; a[1] = v.y; a[2] = v.z; a[3] = v.w;
}

__global__ __launch_bounds__(256) void attn_kernel(
    const float* __restrict__ qu,    // (B,H,T,DK) = query@Wq^T + bq + pos_bias_u
    const float* __restrict__ kh,    // (B,H,T,DK)
    const float* __restrict__ vh,    // (B,H,T,DK)
    const float* __restrict__ ph,    // (H,P,DK)  = pos_emb@Wpos^T
    const float* __restrict__ dpw_g, // (H,P)
    const int*   __restrict__ mask,  // (B,T)
    float* __restrict__ xout)        // (B,T,D)
{
    __shared__ float squ[QT * 64];        // 16 KB, swizzled
    __shared__ float sk[KT * 64];         // 16 KB, swizzled
    __shared__ float sv[KT * 64];         // 16 KB, swizzled
    __shared__ float spw[WIN * 64];       // 32.5 KB, swizzled
    __shared__ float sp[QT][68];          // 17.4 KB, padded (writes/reads 2-way)
    __shared__ float sdpw[WIN];
    __shared__ float smask[KT];

    const int tid = threadIdx.x;
    const int tx = tid & 15, ty = tid >> 4;
    const int bh = blockIdx.x;           // b*H + h
    const int b = bh >> 2, h = bh & 3;   // H == 4
    const int t0 = blockIdx.y * QT;

    const float* qbase = qu + ((size_t)bh * Tc + t0) * DKc;
    const float* kbase = kh + (size_t)bh * Tc * DKc;
    const float* vbase = vh + (size_t)bh * Tc * DKc;
    const float* pbase = ph + (size_t)h * Pc * DKc;

    // Stage Q tile once (reused across all 32 K-tiles)
    #pragma unroll
    for (int r = 0; r < 4; r++) {
        int lin = tid + r * 256;
        int row = lin >> 4, c4 = lin & 15;
        *(float4*)&squ[4 * SW(row, c4)] =
            *(const float4*)(qbase + (size_t)row * DKc + c4 * 4);
    }

    float O[4][4] = {};
    float mrow[4], lrow[4];
    #pragma unroll
    for (int i = 0; i < 4; i++) { mrow[i] = -3.0e38f; lrow[i] = 0.f; }

    for (int kt = 0; kt < Tc / KT; kt++) {
        const int j0 = kt * KT;
        __syncthreads();  // previous iteration's consumers done before restage

        // Stage K,V tiles (64x64) and the 127-row P window (all swizzled)
        #pragma unroll
        for (int r = 0; r < 4; r++) {
            int lin = tid + r * 256;
            int row = lin >> 4, c4 = lin & 15;
            *(float4*)&sk[4 * SW(row, c4)] =
                *(const float4*)(kbase + (size_t)(j0 + row) * DKc + c4 * 4);
            *(float4*)&sv[4 * SW(row, c4)] =
                *(const float4*)(vbase + (size_t)(j0 + row) * DKc + c4 * 4);
        }
        const int relbase = j0 - t0 + Tc - QT;   // rel index of window row w=0, in [0, P-127]
        #pragma unroll
        for (int r = 0; r < 8; r++) {
            int lin = tid + r * 256;
            if (lin < WIN * 16) {
                int row = lin >> 4, c4 = lin & 15;
                *(float4*)&spw[4 * SW(row, c4)] =
                    *(const float4*)(pbase + (size_t)(relbase + row) * DKc + c4 * 4);
            }
        }
        if (tid < WIN) sdpw[tid] = dpw_g[h * Pc + relbase + tid];
        if (tid < KT)  smask[tid] = (mask[b * Tc + j0 + tid] == 0) ? -1e9f : 0.f;
        __syncthreads();

        // ---- scores: s[r][j] = qu[r]·k[j] + qu[r]·pw[w] + dpw[w],  w = j - r + 63
        float s[4][4];
        const int w0 = tx * 4 - ty * 4 + (QT - 1);   // in [3, 123]
        #pragma unroll
        for (int i = 0; i < 4; i++)
            #pragma unroll
            for (int jj = 0; jj < 4; jj++)
                s[i][jj] = sdpw[w0 + jj - i];

        #pragma unroll
        for (int dk4 = 0; dk4 < 16; dk4++) {
            float av[4][4], kv[4][4], pv[7][4];
            #pragma unroll
            for (int i = 0; i < 4; i++)
                f4arr(*(const float4*)&squ[4 * SW(ty * 4 + i, dk4)], av[i]);
            #pragma unroll
            for (int jj = 0; jj < 4; jj++)
                f4arr(*(const float4*)&sk[4 * SW(tx * 4 + jj, dk4)], kv[jj]);
            #pragma unroll
            for (int q = 0; q < 7; q++)
                f4arr(*(const float4*)&spw[4 * SW(w0 - 3 + q, dk4)], pv[q]);
            #pragma unroll
            for (int i = 0; i < 4; i++)
                #pragma unroll
                for (int jj = 0; jj < 4; jj++) {
                    float acc = s[i][jj];
                    #pragma unroll
                    for (int e = 0; e < 4; e++) {
                        acc = fmaf(av[i][e], kv[jj][e], acc);
                        acc = fmaf(av[i][e], pv[jj - i + 3][e], acc);
                    }
                    s[i][jj] = acc;
                }
        }
        #pragma unroll
        for (int i = 0; i < 4; i++)
            #pragma unroll
            for (int jj = 0; jj < 4; jj++)
                s[i][jj] = s[i][jj] * 0.125f + smask[tx * 4 + jj];   // /sqrt(64), mask->-1e9

        // ---- online softmax (row r owned by the 16 lanes sharing ty)
        float tmax[4], tsum[4], pr[4][4];
        #pragma unroll
        for (int i = 0; i < 4; i++)
            tmax[i] = fmaxf(fmaxf(s[i][0], s[i][1]), fmaxf(s[i][2], s[i][3]));
        #pragma unroll
        for (int off = 1; off < 16; off <<= 1)
            #pragma unroll
            for (int i = 0; i < 4; i++)
                tmax[i] = fmaxf(tmax[i], __shfl_xor(tmax[i], off));

        float mnew[4], scl[4];
        #pragma unroll
        for (int i = 0; i < 4; i++) {
            mnew[i] = fmaxf(mrow[i], tmax[i]);
            scl[i]  = __expf(mrow[i] - mnew[i]);   // first tile: exp(-3e38)=0
        }
        #pragma unroll
        for (int i = 0; i < 4; i++) {
            #pragma unroll
            for (int jj = 0; jj < 4; jj++) pr[i][jj] = __expf(s[i][jj] - mnew[i]);
            tsum[i] = (pr[i][0] + pr[i][1]) + (pr[i][2] + pr[i][3]);
        }
        #pragma unroll
        for (int off = 1; off < 16; off <<= 1)
            #pragma unroll
            for (int i = 0; i < 4; i++)
                tsum[i] += __shfl_xor(tsum[i], off);
        #pragma unroll
        for (int i = 0; i < 4; i++) {
            lrow[i] = lrow[i] * scl[i] + tsum[i];
            mrow[i] = mnew[i];
            #pragma unroll
            for (int jj = 0; jj < 4; jj++) O[i][jj] *= scl[i];
        }
        #pragma unroll
        for (int i = 0; i < 4; i++)
            *(float4*)&sp[ty * 4 + i][tx * 4] = make_float4(pr[i][0], pr[i][1], pr[i][2], pr[i][3]);
        __syncthreads();

        // ---- PV: O[r][c] += sum_j p[r][j] * v[j][c]
        #pragma unroll
        for (int j4 = 0; j4 < 16; j4++) {
            float vb[4][4];
            #pragma unroll
            for (int e = 0; e < 4; e++)
                f4arr(*(const float4*)&sv[4 * SW(j4 * 4 + e, tx)], vb[e]);
            #pragma unroll
            for (int i = 0; i < 4; i++) {
                float pa[4];
                f4arr(*(const float4*)&sp[ty * 4 + i][j4 * 4], pa);
                #pragma unroll
                for (int jj = 0; jj < 4; jj++) {
                    float acc = O[i][jj];
                    #pragma unroll
                    for (int e = 0; e < 4; e++) acc = fmaf(pa[e], vb[e][jj], acc);
                    O[i][jj] = acc;
                }
            }
        }
    }

    // ---- epilogue: normalize, write (B,T,D) so the out-proj GEMM reads plain rows
    #pragma unroll
    for (int i = 0; i < 4; i++) {
        float invl = (lrow[i] > 0.f) ? 1.f / lrow[i] : 0.f;
        float4 o4 = make_float4(O[i][0] * invl, O[i][1] * invl, O[i][2] * invl, O[i][3] * invl);
        *(float4*)&xout[((size_t)(b * Tc + t0 + ty * 4 + i)) * Dc + h * DKc + tx * 4] = o4;
    }
}

// ---------------------------------------------------------------------------
extern "C" void kernel_launch(void* const* d_in, const int* in_sizes, int n_in,
                              void* d_out, int out_size, void* d_ws, size_t ws_size,
                              hipStream_t stream) {
    const float* query   = (const float*)d_in[0];
    const float* key_    = (const float*)d_in[1];
    const float* value   = (const float*)d_in[2];
    const float* pos_emb = (const float*)d_in[3];
    const int*   mask    = (const int*)d_in[4];
    const float* Wq  = (const float*)d_in[5];
    const float* bq  = (const float*)d_in[6];
    const float* Wk  = (const float*)d_in[7];
    const float* bk  = (const float*)d_in[8];
    const float* Wv  = (const float*)d_in[9];
    const float* bv  = (const float*)d_in[10];
    const float* Wpos = (const float*)d_in[11];
    const float* pbu = (const float*)d_in[12];
    const float* pbv = (const float*)d_in[13];
    const float* Wo  = (const float*)d_in[14];
    const float* bo  = (const float*)d_in[15];
    float* out = (float*)d_out;

    // Workspace layout (floats); total ~37.9 MB
    float* ws = (float*)d_ws;
    float* qu = ws;                                   // B*H*T*DK = 2097152
    float* kh = qu + (size_t)Bc * Hc * Tc * DKc;      // 2097152
    float* vh = kh + (size_t)Bc * Hc * Tc * DKc;      // 2097152
    float* ph = vh + (size_t)Bc * Hc * Tc * DKc;      // H*P*DK = 1048320 (pad to 1048576)
    float* xh = ph + (size_t)1048576;                 // B*T*D  = 2097152
    float* dpw = xh + (size_t)Bc * Tc * Dc;           // H*P = 16380

    dim3 blk(256);
    // q_u = query@Wq^T + bq + pos_bias_u  (head-split)
    gemm_proj<<<dim3(128, 4), blk, 0, stream>>>(query, Wq, bq, pbu, qu, Bc * Tc, Tc, 1);
    // k, v (head-split)
    gemm_proj<<<dim3(128, 4), blk, 0, stream>>>(key_,  Wk, bk, nullptr, kh, Bc * Tc, Tc, 1);
    gemm_proj<<<dim3(128, 4), blk, 0, stream>>>(value, Wv, bv, nullptr, vh, Bc * Tc, Tc, 1);
    // p = pos_emb@Wpos^T  (head-split, M=P=4095)
    gemm_proj<<<dim3(64, 4), blk, 0, stream>>>(pos_emb, Wpos, nullptr, nullptr, ph, Pc, Pc, 1);
    // dpw[h][w] = (pbv-pbu)[h] . p[h][w]
    dpw_kernel<<<dim3((Hc * Pc + 255) / 256), blk, 0, stream>>>(ph, pbu, pbv, dpw);
    // fused rel-pos flash attention -> xh (B,T,D)
    attn_kernel<<<dim3(Bc * Hc, Tc / QT), blk, 0, stream>>>(qu, kh, vh, ph, dpw, mask, xh);
    // out = xh@Wo^T + bo
    gemm_proj<<<dim3(128, 4), blk, 0, stream>>>(xh, Wo, bo, nullptr, out, Bc * Tc, Tc, 0);
}

// Round 3
// 360.064 us; speedup vs baseline: 2.7339x; 2.7339x over previous
//
#include <hip/hip_runtime.h>
#include <hip/hip_bf16.h>
#include <string.h>

// Problem constants (reference: B=4, T=2048, D=256, H=4, DK=64, P=2T-1)
#define Bc 4
#define Tc 2048
#define Dc 256
#define Hc 4
#define DKc 64
#define Pc 4095

typedef short bf16x8 __attribute__((ext_vector_type(8)));
typedef float f32x4 __attribute__((ext_vector_type(4)));

__device__ __forceinline__ unsigned short f2bs(float x) {
    __bf16 b = (__bf16)x;                       // RNE convert
    return __builtin_bit_cast(unsigned short, b);
}
__device__ __forceinline__ float bs2f(unsigned short u) {
    unsigned int x = ((unsigned int)u) << 16;
    return __builtin_bit_cast(float, x);
}

// ---------------------------------------------------------------------------
// Projection GEMM: out = A @ W^T (+bias)(+add). fp32 math.
// outmode: 0 = f32 flat (M,256); 2 = bf16 head-split (b,h,t,dk).
// ---------------------------------------------------------------------------
__global__ __launch_bounds__(256) void gemm_proj(
    const float* __restrict__ A,
    const float* __restrict__ Wt,
    const float* __restrict__ bias,   // nullable
    const float* __restrict__ addv,   // nullable (pos_bias_u for the q proj)
    void* __restrict__ outp,
    int M, int Tdim, int outmode)
{
    __shared__ float As[16][68];
    __shared__ float Bs[16][68];
    const int tid = threadIdx.x;
    const int tx = tid & 15, ty = tid >> 4;
    const int m0 = blockIdx.x * 64, n0 = blockIdx.y * 64;

    float acc[4][4] = {};

    for (int k0 = 0; k0 < 256; k0 += 16) {
        #pragma unroll
        for (int r = 0; r < 4; r++) {
            int lin = tid + r * 256;
            int mm = lin >> 4, kk = lin & 15;
            int gm = m0 + mm;
            As[kk][mm] = (gm < M) ? A[(size_t)gm * 256 + k0 + kk] : 0.f;
            Bs[kk][mm] = Wt[(size_t)(n0 + mm) * 256 + k0 + kk];
        }
        __syncthreads();
        #pragma unroll
        for (int k = 0; k < 16; k++) {
            float4 a4 = *(const float4*)&As[k][ty * 4];
            float4 b4 = *(const float4*)&Bs[k][tx * 4];
            float av[4] = {a4.x, a4.y, a4.z, a4.w};
            float bv[4] = {b4.x, b4.y, b4.z, b4.w};
            #pragma unroll
            for (int i = 0; i < 4; i++)
                #pragma unroll
                for (int j = 0; j < 4; j++)
                    acc[i][j] = fmaf(av[i], bv[j], acc[i][j]);
        }
        __syncthreads();
    }

    #pragma unroll
    for (int i = 0; i < 4; i++) {
        int gm = m0 + ty * 4 + i;
        if (gm >= M) continue;
        float vrow[4];
        #pragma unroll
        for (int j = 0; j < 4; j++) {
            int gn = n0 + tx * 4 + j;
            float v = acc[i][j];
            if (bias) v += bias[gn];
            if (addv) v += addv[gn];
            vrow[j] = v;
        }
        int gn0 = n0 + tx * 4;
        if (outmode == 2) {
            int bb = gm / Tdim, t = gm % Tdim;
            int hh = gn0 >> 6, dk = gn0 & 63;
            size_t oidx = ((size_t)(bb * Hc + hh) * Tdim + t) * DKc + dk;
            ushort4 pk;
            pk.x = f2bs(vrow[0]); pk.y = f2bs(vrow[1]);
            pk.z = f2bs(vrow[2]); pk.w = f2bs(vrow[3]);
            *(ushort4*)&((unsigned short*)outp)[oidx] = pk;
        } else {
            *(float4*)&((float*)outp)[(size_t)gm * 256 + gn0] =
                make_float4(vrow[0], vrow[1], vrow[2], vrow[3]);
        }
    }
}

// ---------------------------------------------------------------------------
// dpw[h][w] = (pos_bias_v - pos_bias_u)[h] . p[h][w][:]
// ---------------------------------------------------------------------------
__global__ __launch_bounds__(256) void dpw_kernel(
    const unsigned short* __restrict__ ph,   // (H,P,DK) bf16
    const float* __restrict__ pbu,
    const float* __restrict__ pbv,
    float* __restrict__ dpw)                 // (H,P)
{
    int idx = blockIdx.x * 256 + threadIdx.x;
    if (idx >= Hc * Pc) return;
    int h = idx / Pc;
    const unsigned short* row = ph + (size_t)idx * DKc;
    const float* u = pbu + h * DKc;
    const float* v = pbv + h * DKc;
    float acc = 0.f;
    #pragma unroll
    for (int d = 0; d < DKc; d++)
        acc = fmaf(v[d] - u[d], bs2f(row[d]), acc);
    dpw[idx] = acc;
}

// ---------------------------------------------------------------------------
// MFMA flash attention. 256 thr = 4 waves; wave w owns q-rows [16w,16w+16).
// s[t][j] = (qu[t]·k[j] + qu[t]·p[w] + dpw[w])/8 + maskadd, w = j-t+T-1.
// AC: 8 MFMA/wave/tile. BD: wave's 16x79 banded q·p_win^T stripe (10 MFMA)
//   + dpw, bounced via wave-PRIVATE sbdw (no barrier), gathered per-score.
// PV: 8 MFMA, V transposed at stage into (dk,t) with col-XOR swizzle.
// bf16 rows padded to 72 elems (144B) -> balanced LDS banks for b128.
// LDS 77.6KB -> 2 blocks/CU.
// ---------------------------------------------------------------------------
__global__ __launch_bounds__(256) void attn_mfma(
    const unsigned short* __restrict__ qu,   // (B,H,T,DK) bf16, = q + pbu
    const unsigned short* __restrict__ kh,   // (B,H,T,DK) bf16
    const unsigned short* __restrict__ vh,   // (B,H,T,DK) bf16
    const unsigned short* __restrict__ ph,   // (H,P,DK)  bf16
    const float* __restrict__ dpw_g,         // (H,P)
    const int*   __restrict__ mask,          // (B,T)
    float* __restrict__ xout)                // (B,T,D) f32
{
    __shared__ unsigned short sq[64 * 72];
    __shared__ unsigned short sk[64 * 72];
    __shared__ unsigned short svt[64 * 72];   // [dk][t^swz]
    __shared__ unsigned short sp[64 * 72];    // probs, wave-private rows
    __shared__ unsigned short spw[128 * 72];
    __shared__ float sbdw[4][16 * 84];        // wave-private BD stripes
    __shared__ float sdpw[128];
    __shared__ float smask[64];

    const int tid = threadIdx.x;
    const int wv = tid >> 6;
    const int lane = tid & 63;
    const int c = lane & 15, g = lane >> 4;
    const int bh = blockIdx.x, b = bh >> 2, h = bh & 3;
    const int t0 = blockIdx.y * 64;
    const int tb = wv * 16;

    const unsigned short* qbase = qu + ((size_t)bh * Tc + t0) * DKc;
    const unsigned short* kbase = kh + (size_t)bh * Tc * DKc;
    const unsigned short* vbase = vh + (size_t)bh * Tc * DKc;
    const unsigned short* pbase = ph + (size_t)h * Pc * DKc;

    // Stage Q tile once
    #pragma unroll
    for (int r = 0; r < 2; r++) {
        int lin = tid + 256 * r;
        int row = lin >> 3, ch = lin & 7;
        *(uint4*)&sq[row * 72 + ch * 8] =
            *(const uint4*)(qbase + (size_t)row * DKc + ch * 8);
    }

    f32x4 O[4];
    #pragma unroll
    for (int ct = 0; ct < 4; ct++) O[ct] = (f32x4){0.f, 0.f, 0.f, 0.f};
    float mrow[4], lrow[4];
    #pragma unroll
    for (int r = 0; r < 4; r++) { mrow[r] = -3.0e38f; lrow[r] = 0.f; }

    bf16x8 qf0, qf1;

    for (int kt = 0; kt < Tc / 64; kt++) {
        const int j0 = kt * 64;
        __syncthreads();   // all waves done reading sk/svt/spw before restage

        #pragma unroll
        for (int r = 0; r < 2; r++) {
            int lin = tid + 256 * r;
            int row = lin >> 3, ch = lin & 7;
            *(uint4*)&sk[row * 72 + ch * 8] =
                *(const uint4*)(kbase + (size_t)(j0 + row) * DKc + ch * 8);
        }
        #pragma unroll
        for (int r = 0; r < 2; r++) {
            int lin = tid + 256 * r;
            int trow = lin >> 3, ch = lin & 7;
            uint4 raw = *(const uint4*)(vbase + (size_t)(j0 + trow) * DKc + ch * 8);
            unsigned short el[8];
            __builtin_memcpy(el, &raw, 16);
            #pragma unroll
            for (int e = 0; e < 8; e++) {
                int dk = ch * 8 + e;
                svt[dk * 72 + (trow ^ ((dk >> 3) << 3))] = el[e];
            }
        }
        const int relbase = j0 - t0 + (Tc - 64);   // in [0, 3968]
        #pragma unroll
        for (int r = 0; r < 4; r++) {
            int lin = tid + 256 * r;
            int row = lin >> 3, ch = lin & 7;
            int grow = relbase + row;
            if (grow > Pc - 1) grow = Pc - 1;      // row 127 pad (never used)
            *(uint4*)&spw[row * 72 + ch * 8] =
                *(const uint4*)(pbase + (size_t)grow * DKc + ch * 8);
        }
        if (tid < 128) {
            int idx = relbase + tid;
            sdpw[tid] = (idx <= Pc - 1) ? dpw_g[h * Pc + idx] : 0.f;
        }
        if (tid < 64) smask[tid] = (mask[b * Tc + j0 + tid] == 0) ? -1e9f : 0.f;
        __syncthreads();

        if (kt == 0) {
            qf0 = *(const bf16x8*)&sq[(tb + c) * 72 + g * 8];
            qf1 = *(const bf16x8*)&sq[(tb + c) * 72 + (4 + g) * 8];
        }

        // ---- AC: 16x64 score stripe
        f32x4 sac[4];
        #pragma unroll
        for (int ct = 0; ct < 4; ct++) {
            f32x4 acc = (f32x4){0.f, 0.f, 0.f, 0.f};
            bf16x8 kf0 = *(const bf16x8*)&sk[(ct * 16 + c) * 72 + g * 8];
            bf16x8 kf1 = *(const bf16x8*)&sk[(ct * 16 + c) * 72 + (4 + g) * 8];
            acc = __builtin_amdgcn_mfma_f32_16x16x32_bf16(qf0, kf0, acc, 0, 0, 0);
            acc = __builtin_amdgcn_mfma_f32_16x16x32_bf16(qf1, kf1, acc, 0, 0, 0);
            sac[ct] = acc;
        }

        // ---- BD: 16x79 banded stripe -> wave-private LDS (+dpw folded in)
        #pragma unroll
        for (int wt = 0; wt < 5; wt++) {
            f32x4 acc = (f32x4){0.f, 0.f, 0.f, 0.f};
            int prow = (48 - tb) + wt * 16 + c;    // spw row, in [0,127]
            bf16x8 pf0 = *(const bf16x8*)&spw[prow * 72 + g * 8];
            bf16x8 pf1 = *(const bf16x8*)&spw[prow * 72 + (4 + g) * 8];
            acc = __builtin_amdgcn_mfma_f32_16x16x32_bf16(qf0, pf0, acc, 0, 0, 0);
            acc = __builtin_amdgcn_mfma_f32_16x16x32_bf16(qf1, pf1, acc, 0, 0, 0);
            float dpwv = sdpw[(48 - tb) + wt * 16 + c];
            #pragma unroll
            for (int r = 0; r < 4; r++)
                sbdw[wv][(g * 4 + r) * 84 + wt * 16 + c] = acc[r] + dpwv;
        }

        // ---- assemble scores: s = (AC + BD[t][j-t+15]) / 8 + mask
        float sreg[4][4];
        #pragma unroll
        for (int ct = 0; ct < 4; ct++) {
            float madd = smask[ct * 16 + c];
            #pragma unroll
            for (int r = 0; r < 4; r++) {
                int tt = g * 4 + r;
                int x = ct * 16 + c - tt + 15;     // in [0,78]
                sreg[ct][r] = (sac[ct][r] + sbdw[wv][tt * 84 + x]) * 0.125f + madd;
            }
        }

        // ---- online softmax (row tt spans 16 lanes of this g-group)
        float tmax[4], tsum[4];
        #pragma unroll
        for (int r = 0; r < 4; r++)
            tmax[r] = fmaxf(fmaxf(sreg[0][r], sreg[1][r]), fmaxf(sreg[2][r], sreg[3][r]));
        #pragma unroll
        for (int off = 1; off < 16; off <<= 1)
            #pragma unroll
            for (int r = 0; r < 4; r++)
                tmax[r] = fmaxf(tmax[r], __shfl_xor(tmax[r], off));

        float mnew[4], scl[4];
        #pragma unroll
        for (int r = 0; r < 4; r++) {
            mnew[r] = fmaxf(mrow[r], tmax[r]);
            scl[r] = __expf(mrow[r] - mnew[r]);
        }
        float pr[4][4];
        #pragma unroll
        for (int r = 0; r < 4; r++) {
            #pragma unroll
            for (int ct = 0; ct < 4; ct++)
                pr[ct][r] = __expf(sreg[ct][r] - mnew[r]);
            tsum[r] = (pr[0][r] + pr[1][r]) + (pr[2][r] + pr[3][r]);
        }
        #pragma unroll
        for (int off = 1; off < 16; off <<= 1)
            #pragma unroll
            for (int r = 0; r < 4; r++)
                tsum[r] += __shfl_xor(tsum[r], off);
        #pragma unroll
        for (int r = 0; r < 4; r++) {
            lrow[r] = lrow[r] * scl[r] + tsum[r];
            mrow[r] = mnew[r];
        }
        #pragma unroll
        for (int ct = 0; ct < 4; ct++) {
            f32x4 o = O[ct];
            o[0] *= scl[0]; o[1] *= scl[1]; o[2] *= scl[2]; o[3] *= scl[3];
            O[ct] = o;
        }

        // ---- P -> bf16 LDS (wave-private rows), then PV
        #pragma unroll
        for (int ct = 0; ct < 4; ct++)
            #pragma unroll
            for (int r = 0; r < 4; r++)
                sp[(tb + g * 4 + r) * 72 + ct * 16 + c] = f2bs(pr[ct][r]);

        #pragma unroll
        for (int js = 0; js < 2; js++) {
            bf16x8 pfrag = *(const bf16x8*)&sp[(tb + c) * 72 + (js * 4 + g) * 8];
            #pragma unroll
            for (int ct = 0; ct < 4; ct++) {
                int dk = ct * 16 + c;
                int tcol = (js * 32 + g * 8) ^ ((dk >> 3) << 3);
                bf16x8 vf = *(const bf16x8*)&svt[dk * 72 + tcol];
                O[ct] = __builtin_amdgcn_mfma_f32_16x16x32_bf16(pfrag, vf, O[ct], 0, 0, 0);
            }
        }
    }

    // ---- epilogue: normalize, write f32 (B,T,D)
    float invl[4];
    #pragma unroll
    for (int r = 0; r < 4; r++)
        invl[r] = (lrow[r] > 0.f) ? 1.f / lrow[r] : 0.f;
    #pragma unroll
    for (int ct = 0; ct < 4; ct++)
        #pragma unroll
        for (int r = 0; r < 4; r++)
            xout[((size_t)(b * Tc + t0 + tb + g * 4 + r)) * Dc + h * DKc + ct * 16 + c] =
                O[ct][r] * invl[r];
}

// ---------------------------------------------------------------------------
extern "C" void kernel_launch(void* const* d_in, const int* in_sizes, int n_in,
                              void* d_out, int out_size, void* d_ws, size_t ws_size,
                              hipStream_t stream) {
    const float* query   = (const float*)d_in[0];
    const float* key_    = (const float*)d_in[1];
    const float* value   = (const float*)d_in[2];
    const float* pos_emb = (const float*)d_in[3];
    const int*   mask    = (const int*)d_in[4];
    const float* Wq  = (const float*)d_in[5];
    const float* bq  = (const float*)d_in[6];
    const float* Wk  = (const float*)d_in[7];
    const float* bk  = (const float*)d_in[8];
    const float* Wv  = (const float*)d_in[9];
    const float* bv  = (const float*)d_in[10];
    const float* Wpos = (const float*)d_in[11];
    const float* pbu = (const float*)d_in[12];
    const float* pbv = (const float*)d_in[13];
    const float* Wo  = (const float*)d_in[14];
    const float* bo  = (const float*)d_in[15];
    float* out = (float*)d_out;

    // Workspace layout
    char* ws = (char*)d_ws;
    unsigned short* qu_b = (unsigned short*)ws;                    // 4 MB
    unsigned short* kh_b = qu_b + (size_t)Bc * Hc * Tc * DKc;      // 4 MB
    unsigned short* vh_b = kh_b + (size_t)Bc * Hc * Tc * DKc;      // 4 MB
    unsigned short* ph_b = vh_b + (size_t)Bc * Hc * Tc * DKc;      // 2 MB (padded)
    float* dpw = (float*)(ph_b + (size_t)1048576);                 // 64 KB
    float* xh  = dpw + 65536 / 4;                                  // 8 MB
    // total ~22 MB

    dim3 blk(256);
    gemm_proj<<<dim3(128, 4), blk, 0, stream>>>(query, Wq, bq, pbu, qu_b, Bc * Tc, Tc, 2);
    gemm_proj<<<dim3(128, 4), blk, 0, stream>>>(key_,  Wk, bk, nullptr, kh_b, Bc * Tc, Tc, 2);
    gemm_proj<<<dim3(128, 4), blk, 0, stream>>>(value, Wv, bv, nullptr, vh_b, Bc * Tc, Tc, 2);
    gemm_proj<<<dim3(64, 4),  blk, 0, stream>>>(pos_emb, Wpos, nullptr, nullptr, ph_b, Pc, Pc, 2);
    dpw_kernel<<<dim3((Hc * Pc + 255) / 256), blk, 0, stream>>>(ph_b, pbu, pbv, dpw);
    attn_mfma<<<dim3(Bc * Hc, Tc / 64), blk, 0, stream>>>(qu_b, kh_b, vh_b, ph_b, dpw, mask, xh);
    gemm_proj<<<dim3(128, 4), blk, 0, stream>>>(xh, Wo, bo, nullptr, out, Bc * Tc, Tc, 0);
}

// Round 4
// 246.851 us; speedup vs baseline: 3.9878x; 1.4586x over previous
//
#include <hip/hip_runtime.h>
#include <hip/hip_bf16.h>
#include <string.h>

// Problem constants (reference: B=4, T=2048, D=256, H=4, DK=64, P=2T-1)
#define Bc 4
#define Tc 2048
#define Dc 256
#define Hc 4
#define DKc 64
#define Pc 4095

typedef short bf16x8 __attribute__((ext_vector_type(8)));
typedef float f32x4 __attribute__((ext_vector_type(4)));

__device__ __forceinline__ unsigned short f2bs(float x) {
    __bf16 b = (__bf16)x;                       // RNE convert
    return __builtin_bit_cast(unsigned short, b);
}
__device__ __forceinline__ float bs2f(unsigned short u) {
    unsigned int x = ((unsigned int)u) << 16;
    return __builtin_bit_cast(float, x);
}

// ---------------------------------------------------------------------------
// Split Wo (256x256 f32) into bf16 hi + bf16 lo residual.
// ---------------------------------------------------------------------------
__global__ __launch_bounds__(256) void wsplit_kernel(
    const float* __restrict__ W,
    unsigned short* __restrict__ Whi,
    unsigned short* __restrict__ Wlo)
{
    int i = blockIdx.x * 256 + threadIdx.x;
    if (i >= Dc * Dc) return;
    float w = W[i];
    unsigned short h = f2bs(w);
    Whi[i] = h;
    Wlo[i] = f2bs(w - bs2f(h));
}

// ---------------------------------------------------------------------------
// bf16-MFMA projection GEMM: out = bf16( A @ W^T (+bias)(+add) ), head-split
// (b,h,t,dk) layout. A,(M,256) f32 cast to bf16 at stage; W (256,256) f32.
// 64x64 tile, BK=64, 4 waves x 16-row stripes, 8 MFMA(16x16x32)/wave/K-step.
// LDS rows padded to 72 shorts (144B): staging b128 writes and frag b128
// reads both hit 8 lanes / 4-bank group = wave64 minimum (no conflicts).
// ---------------------------------------------------------------------------
__global__ __launch_bounds__(256) void gemm_mfma_proj(
    const float* __restrict__ A,
    const float* __restrict__ Wt,
    const float* __restrict__ bias,   // nullable
    const float* __restrict__ addv,   // nullable (pos_bias_u for q)
    unsigned short* __restrict__ outp,
    int M, int Tdim)
{
    __shared__ unsigned short sa[64 * 72];
    __shared__ unsigned short sb[64 * 72];
    const int tid = threadIdx.x;
    const int wv = tid >> 6, lane = tid & 63;
    const int c = lane & 15, g = lane >> 4;
    const int m0 = blockIdx.x * 64, n0 = blockIdx.y * 64;
    const int tb = wv * 16;

    f32x4 acc[4];
    #pragma unroll
    for (int ct = 0; ct < 4; ct++) acc[ct] = (f32x4){0.f, 0.f, 0.f, 0.f};

    for (int k0 = 0; k0 < 256; k0 += 64) {
        if (k0) __syncthreads();
        #pragma unroll
        for (int r = 0; r < 2; r++) {
            int lin = tid + 256 * r;
            int row = lin >> 3, ch = lin & 7;
            int gm = m0 + row;
            float4 f0, f1;
            if (gm < M) {
                f0 = *(const float4*)(A + (size_t)gm * 256 + k0 + ch * 8);
                f1 = *(const float4*)(A + (size_t)gm * 256 + k0 + ch * 8 + 4);
            } else {
                f0 = make_float4(0.f, 0.f, 0.f, 0.f); f1 = f0;
            }
            unsigned short pa[8] = {f2bs(f0.x), f2bs(f0.y), f2bs(f0.z), f2bs(f0.w),
                                    f2bs(f1.x), f2bs(f1.y), f2bs(f1.z), f2bs(f1.w)};
            *(uint4*)&sa[row * 72 + ch * 8] = *(const uint4*)pa;

            float4 w0 = *(const float4*)(Wt + (size_t)(n0 + row) * 256 + k0 + ch * 8);
            float4 w1 = *(const float4*)(Wt + (size_t)(n0 + row) * 256 + k0 + ch * 8 + 4);
            unsigned short pb[8] = {f2bs(w0.x), f2bs(w0.y), f2bs(w0.z), f2bs(w0.w),
                                    f2bs(w1.x), f2bs(w1.y), f2bs(w1.z), f2bs(w1.w)};
            *(uint4*)&sb[row * 72 + ch * 8] = *(const uint4*)pb;
        }
        __syncthreads();
        #pragma unroll
        for (int kk = 0; kk < 2; kk++) {
            bf16x8 af = *(const bf16x8*)&sa[(tb + c) * 72 + kk * 32 + g * 8];
            #pragma unroll
            for (int ct = 0; ct < 4; ct++) {
                bf16x8 bf = *(const bf16x8*)&sb[(ct * 16 + c) * 72 + kk * 32 + g * 8];
                acc[ct] = __builtin_amdgcn_mfma_f32_16x16x32_bf16(af, bf, acc[ct], 0, 0, 0);
            }
        }
    }

    // Epilogue: bias/add, bf16, bounce via sa for 16B-coalesced head-split writes
    __syncthreads();
    #pragma unroll
    for (int ct = 0; ct < 4; ct++) {
        int n = n0 + ct * 16 + c;
        float badd = (bias ? bias[n] : 0.f) + (addv ? addv[n] : 0.f);
        #pragma unroll
        for (int r = 0; r < 4; r++)
            sa[(tb + g * 4 + r) * 72 + ct * 16 + c] = f2bs(acc[ct][r] + badd);
    }
    __syncthreads();
    const int hh = n0 >> 6;
    #pragma unroll
    for (int r = 0; r < 2; r++) {
        int lin = tid + 256 * r;
        int row = lin >> 3, ch = lin & 7;
        int gm = m0 + row;
        if (gm >= M) continue;
        int bb = gm / Tdim, t = gm - bb * Tdim;
        size_t oidx = ((size_t)(bb * Hc + hh) * Tdim + t) * DKc + ch * 8;
        *(uint4*)&outp[oidx] = *(const uint4*)&sa[row * 72 + ch * 8];
    }
}

// ---------------------------------------------------------------------------
// Output projection with hi/lo split (fp32-grade): out = x @ Wo^T + bo,
// x ~ xhi + xlo, Wo ~ Whi + Wlo; out = xhi*Whi + xhi*Wlo + xlo*Whi (+bo).
// ---------------------------------------------------------------------------
__global__ __launch_bounds__(256) void gemm_out_split(
    const unsigned short* __restrict__ Ahi,
    const unsigned short* __restrict__ Alo,
    const unsigned short* __restrict__ Whi,
    const unsigned short* __restrict__ Wlo,
    const float* __restrict__ bias,
    float* __restrict__ outp, int M)
{
    __shared__ unsigned short sah[64 * 72];
    __shared__ unsigned short sal[64 * 72];
    __shared__ unsigned short sbh[64 * 72];
    __shared__ unsigned short sbl[64 * 72];
    __shared__ float sout[64 * 68];
    const int tid = threadIdx.x;
    const int wv = tid >> 6, lane = tid & 63;
    const int c = lane & 15, g = lane >> 4;
    const int m0 = blockIdx.x * 64, n0 = blockIdx.y * 64;
    const int tb = wv * 16;

    f32x4 acc[4];
    #pragma unroll
    for (int ct = 0; ct < 4; ct++) acc[ct] = (f32x4){0.f, 0.f, 0.f, 0.f};

    for (int k0 = 0; k0 < 256; k0 += 64) {
        if (k0) __syncthreads();
        #pragma unroll
        for (int r = 0; r < 2; r++) {
            int lin = tid + 256 * r;
            int row = lin >> 3, ch = lin & 7;
            size_t asrc = (size_t)(m0 + row) * 256 + k0 + ch * 8;
            size_t wsrc = (size_t)(n0 + row) * 256 + k0 + ch * 8;
            *(uint4*)&sah[row * 72 + ch * 8] = *(const uint4*)(Ahi + asrc);
            *(uint4*)&sal[row * 72 + ch * 8] = *(const uint4*)(Alo + asrc);
            *(uint4*)&sbh[row * 72 + ch * 8] = *(const uint4*)(Whi + wsrc);
            *(uint4*)&sbl[row * 72 + ch * 8] = *(const uint4*)(Wlo + wsrc);
        }
        __syncthreads();
        #pragma unroll
        for (int kk = 0; kk < 2; kk++) {
            bf16x8 ah = *(const bf16x8*)&sah[(tb + c) * 72 + kk * 32 + g * 8];
            bf16x8 al = *(const bf16x8*)&sal[(tb + c) * 72 + kk * 32 + g * 8];
            #pragma unroll
            for (int ct = 0; ct < 4; ct++) {
                bf16x8 bh = *(const bf16x8*)&sbh[(ct * 16 + c) * 72 + kk * 32 + g * 8];
                bf16x8 bl = *(const bf16x8*)&sbl[(ct * 16 + c) * 72 + kk * 32 + g * 8];
                acc[ct] = __builtin_amdgcn_mfma_f32_16x16x32_bf16(ah, bh, acc[ct], 0, 0, 0);
                acc[ct] = __builtin_amdgcn_mfma_f32_16x16x32_bf16(ah, bl, acc[ct], 0, 0, 0);
                acc[ct] = __builtin_amdgcn_mfma_f32_16x16x32_bf16(al, bh, acc[ct], 0, 0, 0);
            }
        }
    }

    __syncthreads();
    #pragma unroll
    for (int ct = 0; ct < 4; ct++) {
        float b = bias[n0 + ct * 16 + c];
        #pragma unroll
        for (int r = 0; r < 4; r++)
            sout[(tb + g * 4 + r) * 68 + ct * 16 + c] = acc[ct][r] + b;
    }
    __syncthreads();
    #pragma unroll
    for (int r = 0; r < 4; r++) {
        int lin = tid + 256 * r;
        int row = lin >> 4, c4 = lin & 15;
        float4 v = *(const float4*)&sout[row * 68 + c4 * 4];
        *(float4*)&outp[(size_t)(m0 + row) * 256 + n0 + c4 * 4] = v;
    }
}

// ---------------------------------------------------------------------------
// dpw[h][w] = (pos_bias_v - pos_bias_u)[h] . p[h][w][:]
// ---------------------------------------------------------------------------
__global__ __launch_bounds__(256) void dpw_kernel(
    const unsigned short* __restrict__ ph,   // (H,P,DK) bf16
    const float* __restrict__ pbu,
    const float* __restrict__ pbv,
    float* __restrict__ dpw)                 // (H,P)
{
    int idx = blockIdx.x * 256 + threadIdx.x;
    if (idx >= Hc * Pc) return;
    int h = idx / Pc;
    const unsigned short* row = ph + (size_t)idx * DKc;
    const float* u = pbu + h * DKc;
    const float* v = pbv + h * DKc;
    float acc = 0.f;
    #pragma unroll
    for (int d = 0; d < DKc; d++)
        acc = fmaf(v[d] - u[d], bs2f(row[d]), acc);
    dpw[idx] = acc;
}

// ---------------------------------------------------------------------------
// MFMA flash attention (validated round 3). Epilogue now writes x as
// bf16 hi + bf16 lo residual for the split out-projection.
// ---------------------------------------------------------------------------
__global__ __launch_bounds__(256) void attn_mfma(
    const unsigned short* __restrict__ qu,   // (B,H,T,DK) bf16, = q + pbu
    const unsigned short* __restrict__ kh,   // (B,H,T,DK) bf16
    const unsigned short* __restrict__ vh,   // (B,H,T,DK) bf16
    const unsigned short* __restrict__ ph,   // (H,P,DK)  bf16
    const float* __restrict__ dpw_g,         // (H,P)
    const int*   __restrict__ mask,          // (B,T)
    unsigned short* __restrict__ xhi,        // (B,T,D) bf16 hi
    unsigned short* __restrict__ xlo)        // (B,T,D) bf16 lo
{
    __shared__ unsigned short sq[64 * 72];
    __shared__ unsigned short sk[64 * 72];
    __shared__ unsigned short svt[64 * 72];   // [dk][t^swz]
    __shared__ unsigned short sp[64 * 72];    // probs, wave-private rows
    __shared__ unsigned short spw[128 * 72];
    __shared__ float sbdw[4][16 * 84];        // wave-private BD stripes
    __shared__ float sdpw[128];
    __shared__ float smask[64];

    const int tid = threadIdx.x;
    const int wv = tid >> 6;
    const int lane = tid & 63;
    const int c = lane & 15, g = lane >> 4;
    const int bh = blockIdx.x, b = bh >> 2, h = bh & 3;
    const int t0 = blockIdx.y * 64;
    const int tb = wv * 16;

    const unsigned short* qbase = qu + ((size_t)bh * Tc + t0) * DKc;
    const unsigned short* kbase = kh + (size_t)bh * Tc * DKc;
    const unsigned short* vbase = vh + (size_t)bh * Tc * DKc;
    const unsigned short* pbase = ph + (size_t)h * Pc * DKc;

    #pragma unroll
    for (int r = 0; r < 2; r++) {
        int lin = tid + 256 * r;
        int row = lin >> 3, ch = lin & 7;
        *(uint4*)&sq[row * 72 + ch * 8] =
            *(const uint4*)(qbase + (size_t)row * DKc + ch * 8);
    }

    f32x4 O[4];
    #pragma unroll
    for (int ct = 0; ct < 4; ct++) O[ct] = (f32x4){0.f, 0.f, 0.f, 0.f};
    float mrow[4], lrow[4];
    #pragma unroll
    for (int r = 0; r < 4; r++) { mrow[r] = -3.0e38f; lrow[r] = 0.f; }

    bf16x8 qf0, qf1;

    for (int kt = 0; kt < Tc / 64; kt++) {
        const int j0 = kt * 64;
        __syncthreads();

        #pragma unroll
        for (int r = 0; r < 2; r++) {
            int lin = tid + 256 * r;
            int row = lin >> 3, ch = lin & 7;
            *(uint4*)&sk[row * 72 + ch * 8] =
                *(const uint4*)(kbase + (size_t)(j0 + row) * DKc + ch * 8);
        }
        #pragma unroll
        for (int r = 0; r < 2; r++) {
            int lin = tid + 256 * r;
            int trow = lin >> 3, ch = lin & 7;
            uint4 raw = *(const uint4*)(vbase + (size_t)(j0 + trow) * DKc + ch * 8);
            unsigned short el[8];
            __builtin_memcpy(el, &raw, 16);
            #pragma unroll
            for (int e = 0; e < 8; e++) {
                int dk = ch * 8 + e;
                svt[dk * 72 + (trow ^ ((dk >> 3) << 3))] = el[e];
            }
        }
        const int relbase = j0 - t0 + (Tc - 64);
        #pragma unroll
        for (int r = 0; r < 4; r++) {
            int lin = tid + 256 * r;
            int row = lin >> 3, ch = lin & 7;
            int grow = relbase + row;
            if (grow > Pc - 1) grow = Pc - 1;
            *(uint4*)&spw[row * 72 + ch * 8] =
                *(const uint4*)(pbase + (size_t)grow * DKc + ch * 8);
        }
        if (tid < 128) {
            int idx = relbase + tid;
            sdpw[tid] = (idx <= Pc - 1) ? dpw_g[h * Pc + idx] : 0.f;
        }
        if (tid < 64) smask[tid] = (mask[b * Tc + j0 + tid] == 0) ? -1e9f : 0.f;
        __syncthreads();

        if (kt == 0) {
            qf0 = *(const bf16x8*)&sq[(tb + c) * 72 + g * 8];
            qf1 = *(const bf16x8*)&sq[(tb + c) * 72 + (4 + g) * 8];
        }

        f32x4 sac[4];
        #pragma unroll
        for (int ct = 0; ct < 4; ct++) {
            f32x4 acc = (f32x4){0.f, 0.f, 0.f, 0.f};
            bf16x8 kf0 = *(const bf16x8*)&sk[(ct * 16 + c) * 72 + g * 8];
            bf16x8 kf1 = *(const bf16x8*)&sk[(ct * 16 + c) * 72 + (4 + g) * 8];
            acc = __builtin_amdgcn_mfma_f32_16x16x32_bf16(qf0, kf0, acc, 0, 0, 0);
            acc = __builtin_amdgcn_mfma_f32_16x16x32_bf16(qf1, kf1, acc, 0, 0, 0);
            sac[ct] = acc;
        }

        #pragma unroll
        for (int wt = 0; wt < 5; wt++) {
            f32x4 acc = (f32x4){0.f, 0.f, 0.f, 0.f};
            int prow = (48 - tb) + wt * 16 + c;
            bf16x8 pf0 = *(const bf16x8*)&spw[prow * 72 + g * 8];
            bf16x8 pf1 = *(const bf16x8*)&spw[prow * 72 + (4 + g) * 8];
            acc = __builtin_amdgcn_mfma_f32_16x16x32_bf16(qf0, pf0, acc, 0, 0, 0);
            acc = __builtin_amdgcn_mfma_f32_16x16x32_bf16(qf1, pf1, acc, 0, 0, 0);
            float dpwv = sdpw[(48 - tb) + wt * 16 + c];
            #pragma unroll
            for (int r = 0; r < 4; r++)
                sbdw[wv][(g * 4 + r) * 84 + wt * 16 + c] = acc[r] + dpwv;
        }

        float sreg[4][4];
        #pragma unroll
        for (int ct = 0; ct < 4; ct++) {
            float madd = smask[ct * 16 + c];
            #pragma unroll
            for (int r = 0; r < 4; r++) {
                int tt = g * 4 + r;
                int x = ct * 16 + c - tt + 15;
                sreg[ct][r] = (sac[ct][r] + sbdw[wv][tt * 84 + x]) * 0.125f + madd;
            }
        }

        float tmax[4], tsum[4];
        #pragma unroll
        for (int r = 0; r < 4; r++)
            tmax[r] = fmaxf(fmaxf(sreg[0][r], sreg[1][r]), fmaxf(sreg[2][r], sreg[3][r]));
        #pragma unroll
        for (int off = 1; off < 16; off <<= 1)
            #pragma unroll
            for (int r = 0; r < 4; r++)
                tmax[r] = fmaxf(tmax[r], __shfl_xor(tmax[r], off));

        float mnew[4], scl[4];
        #pragma unroll
        for (int r = 0; r < 4; r++) {
            mnew[r] = fmaxf(mrow[r], tmax[r]);
            scl[r] = __expf(mrow[r] - mnew[r]);
        }
        float pr[4][4];
        #pragma unroll
        for (int r = 0; r < 4; r++) {
            #pragma unroll
            for (int ct = 0; ct < 4; ct++)
                pr[ct][r] = __expf(sreg[ct][r] - mnew[r]);
            tsum[r] = (pr[0][r] + pr[1][r]) + (pr[2][r] + pr[3][r]);
        }
        #pragma unroll
        for (int off = 1; off < 16; off <<= 1)
            #pragma unroll
            for (int r = 0; r < 4; r++)
                tsum[r] += __shfl_xor(tsum[r], off);
        #pragma unroll
        for (int r = 0; r < 4; r++) {
            lrow[r] = lrow[r] * scl[r] + tsum[r];
            mrow[r] = mnew[r];
        }
        #pragma unroll
        for (int ct = 0; ct < 4; ct++) {
            f32x4 o = O[ct];
            o[0] *= scl[0]; o[1] *= scl[1]; o[2] *= scl[2]; o[3] *= scl[3];
            O[ct] = o;
        }

        #pragma unroll
        for (int ct = 0; ct < 4; ct++)
            #pragma unroll
            for (int r = 0; r < 4; r++)
                sp[(tb + g * 4 + r) * 72 + ct * 16 + c] = f2bs(pr[ct][r]);

        #pragma unroll
        for (int js = 0; js < 2; js++) {
            bf16x8 pfrag = *(const bf16x8*)&sp[(tb + c) * 72 + (js * 4 + g) * 8];
            #pragma unroll
            for (int ct = 0; ct < 4; ct++) {
                int dk = ct * 16 + c;
                int tcol = (js * 32 + g * 8) ^ ((dk >> 3) << 3);
                bf16x8 vf = *(const bf16x8*)&svt[dk * 72 + tcol];
                O[ct] = __builtin_amdgcn_mfma_f32_16x16x32_bf16(pfrag, vf, O[ct], 0, 0, 0);
            }
        }
    }

    // ---- epilogue: normalize, write bf16 hi + lo residual
    float invl[4];
    #pragma unroll
    for (int r = 0; r < 4; r++)
        invl[r] = (lrow[r] > 0.f) ? 1.f / lrow[r] : 0.f;
    #pragma unroll
    for (int ct = 0; ct < 4; ct++)
        #pragma unroll
        for (int r = 0; r < 4; r++) {
            size_t idx = ((size_t)(b * Tc + t0 + tb + g * 4 + r)) * Dc + h * DKc + ct * 16 + c;
            float v = O[ct][r] * invl[r];
            unsigned short hi = f2bs(v);
            xhi[idx] = hi;
            xlo[idx] = f2bs(v - bs2f(hi));
        }
}

// ---------------------------------------------------------------------------
extern "C" void kernel_launch(void* const* d_in, const int* in_sizes, int n_in,
                              void* d_out, int out_size, void* d_ws, size_t ws_size,
                              hipStream_t stream) {
    const float* query   = (const float*)d_in[0];
    const float* key_    = (const float*)d_in[1];
    const float* value   = (const float*)d_in[2];
    const float* pos_emb = (const float*)d_in[3];
    const int*   mask    = (const int*)d_in[4];
    const float* Wq  = (const float*)d_in[5];
    const float* bq  = (const float*)d_in[6];
    const float* Wk  = (const float*)d_in[7];
    const float* bk  = (const float*)d_in[8];
    const float* Wv  = (const float*)d_in[9];
    const float* bv  = (const float*)d_in[10];
    const float* Wpos = (const float*)d_in[11];
    const float* pbu = (const float*)d_in[12];
    const float* pbv = (const float*)d_in[13];
    const float* Wo  = (const float*)d_in[14];
    const float* bo  = (const float*)d_in[15];
    float* out = (float*)d_out;

    // Workspace layout (~22.5 MB)
    const size_t NQ = (size_t)Bc * Hc * Tc * DKc;       // 2,097,152
    unsigned short* qu_b = (unsigned short*)d_ws;
    unsigned short* kh_b = qu_b + NQ;
    unsigned short* vh_b = kh_b + NQ;
    unsigned short* ph_b = vh_b + NQ;                   // 1,048,576 slot
    unsigned short* xhi  = ph_b + 1048576;
    unsigned short* xlo  = xhi + NQ;
    unsigned short* wo_hi = xlo + NQ;                   // 65,536
    unsigned short* wo_lo = wo_hi + 65536;
    float* dpw = (float*)(wo_lo + 65536);               // 16,380 floats

    dim3 blk(256);
    wsplit_kernel<<<dim3(Dc * Dc / 256), blk, 0, stream>>>(Wo, wo_hi, wo_lo);
    gemm_mfma_proj<<<dim3(128, 4), blk, 0, stream>>>(query, Wq, bq, pbu, qu_b, Bc * Tc, Tc);
    gemm_mfma_proj<<<dim3(128, 4), blk, 0, stream>>>(key_,  Wk, bk, nullptr, kh_b, Bc * Tc, Tc);
    gemm_mfma_proj<<<dim3(128, 4), blk, 0, stream>>>(value, Wv, bv, nullptr, vh_b, Bc * Tc, Tc);
    gemm_mfma_proj<<<dim3(64, 4),  blk, 0, stream>>>(pos_emb, Wpos, nullptr, nullptr, ph_b, Pc, Pc);
    dpw_kernel<<<dim3((Hc * Pc + 255) / 256), blk, 0, stream>>>(ph_b, pbu, pbv, dpw);
    attn_mfma<<<dim3(Bc * Hc, Tc / 64), blk, 0, stream>>>(qu_b, kh_b, vh_b, ph_b, dpw, mask, xhi, xlo);
    gemm_out_split<<<dim3(128, 4), blk, 0, stream>>>(xhi, xlo, wo_hi, wo_lo, bo, out, Bc * Tc);
}

// Round 5
// 245.790 us; speedup vs baseline: 4.0050x; 1.0043x over previous
//
#include <hip/hip_runtime.h>
#include <hip/hip_bf16.h>
#include <string.h>

// Problem constants (reference: B=4, T=2048, D=256, H=4, DK=64, P=2T-1)
#define Bc 4
#define Tc 2048
#define Dc 256
#define Hc 4
#define DKc 64
#define Pc 4095

typedef short bf16x8 __attribute__((ext_vector_type(8)));
typedef float f32x4 __attribute__((ext_vector_type(4)));

__device__ __forceinline__ unsigned short f2bs(float x) {
    __bf16 b = (__bf16)x;                       // RNE convert
    return __builtin_bit_cast(unsigned short, b);
}
__device__ __forceinline__ float bs2f(unsigned short u) {
    unsigned int x = ((unsigned int)u) << 16;
    return __builtin_bit_cast(float, x);
}

// ---------------------------------------------------------------------------
// Shared bf16-MFMA GEMM body: out = bf16( scale * (A @ W^T + bias + addv) ),
// head-split (b,h,t,dk). 64x64 tile, BK=64, 4 waves, 8 MFMA/wave/K-step.
// LDS rows padded to 72 shorts (144B) -> conflict-free b128 reads/writes.
// ---------------------------------------------------------------------------
__device__ __forceinline__ void gemm_body(
    const float* __restrict__ A, const float* __restrict__ Wt,
    const float* __restrict__ bias, const float* __restrict__ addv,
    unsigned short* __restrict__ outp, int M, int Tdim, float scale,
    unsigned short* sa, unsigned short* sb)
{
    const int tid = threadIdx.x;
    const int wv = tid >> 6, lane = tid & 63;
    const int c = lane & 15, g = lane >> 4;
    const int m0 = blockIdx.x * 64, n0 = blockIdx.y * 64;
    const int tb = wv * 16;

    f32x4 acc[4];
    #pragma unroll
    for (int ct = 0; ct < 4; ct++) acc[ct] = (f32x4){0.f, 0.f, 0.f, 0.f};

    for (int k0 = 0; k0 < 256; k0 += 64) {
        if (k0) __syncthreads();
        #pragma unroll
        for (int r = 0; r < 2; r++) {
            int lin = tid + 256 * r;
            int row = lin >> 3, ch = lin & 7;
            int gm = m0 + row;
            float4 f0, f1;
            if (gm < M) {
                f0 = *(const float4*)(A + (size_t)gm * 256 + k0 + ch * 8);
                f1 = *(const float4*)(A + (size_t)gm * 256 + k0 + ch * 8 + 4);
            } else {
                f0 = make_float4(0.f, 0.f, 0.f, 0.f); f1 = f0;
            }
            unsigned short pa[8] = {f2bs(f0.x), f2bs(f0.y), f2bs(f0.z), f2bs(f0.w),
                                    f2bs(f1.x), f2bs(f1.y), f2bs(f1.z), f2bs(f1.w)};
            *(uint4*)&sa[row * 72 + ch * 8] = *(const uint4*)pa;

            float4 w0 = *(const float4*)(Wt + (size_t)(n0 + row) * 256 + k0 + ch * 8);
            float4 w1 = *(const float4*)(Wt + (size_t)(n0 + row) * 256 + k0 + ch * 8 + 4);
            unsigned short pb[8] = {f2bs(w0.x), f2bs(w0.y), f2bs(w0.z), f2bs(w0.w),
                                    f2bs(w1.x), f2bs(w1.y), f2bs(w1.z), f2bs(w1.w)};
            *(uint4*)&sb[row * 72 + ch * 8] = *(const uint4*)pb;
        }
        __syncthreads();
        #pragma unroll
        for (int kk = 0; kk < 2; kk++) {
            bf16x8 af = *(const bf16x8*)&sa[(tb + c) * 72 + kk * 32 + g * 8];
            #pragma unroll
            for (int ct = 0; ct < 4; ct++) {
                bf16x8 bf = *(const bf16x8*)&sb[(ct * 16 + c) * 72 + kk * 32 + g * 8];
                acc[ct] = __builtin_amdgcn_mfma_f32_16x16x32_bf16(af, bf, acc[ct], 0, 0, 0);
            }
        }
    }

    __syncthreads();
    #pragma unroll
    for (int ct = 0; ct < 4; ct++) {
        int n = n0 + ct * 16 + c;
        float badd = (bias ? bias[n] : 0.f) + (addv ? addv[n] : 0.f);
        #pragma unroll
        for (int r = 0; r < 4; r++)
            sa[(tb + g * 4 + r) * 72 + ct * 16 + c] = f2bs((acc[ct][r] + badd) * scale);
    }
    __syncthreads();
    const int hh = n0 >> 6;
    #pragma unroll
    for (int r = 0; r < 2; r++) {
        int lin = tid + 256 * r;
        int row = lin >> 3, ch = lin & 7;
        int gm = m0 + row;
        if (gm >= M) continue;
        int bb = gm / Tdim, t = gm - bb * Tdim;
        size_t oidx = ((size_t)(bb * Hc + hh) * Tdim + t) * DKc + ch * 8;
        *(uint4*)&outp[oidx] = *(const uint4*)&sa[row * 72 + ch * 8];
    }
}

// ---------------------------------------------------------------------------
// Fused q/k/v projections (blockIdx.z selects). q is pre-scaled by 1/8.
// ---------------------------------------------------------------------------
__global__ __launch_bounds__(256) void gemm_qkv(
    const float* __restrict__ q, const float* __restrict__ k, const float* __restrict__ v,
    const float* __restrict__ Wq, const float* __restrict__ bq,
    const float* __restrict__ Wk, const float* __restrict__ bk,
    const float* __restrict__ Wv, const float* __restrict__ bv,
    const float* __restrict__ pbu,
    unsigned short* __restrict__ qo, unsigned short* __restrict__ ko,
    unsigned short* __restrict__ vo)
{
    __shared__ unsigned short sa[64 * 72];
    __shared__ unsigned short sb[64 * 72];
    const float *A, *Wt, *bias, *addv; unsigned short* outp; float scale;
    if (blockIdx.z == 0)      { A = q; Wt = Wq; bias = bq; addv = pbu;    outp = qo; scale = 0.125f; }
    else if (blockIdx.z == 1) { A = k; Wt = Wk; bias = bk; addv = nullptr; outp = ko; scale = 1.f; }
    else                      { A = v; Wt = Wv; bias = bv; addv = nullptr; outp = vo; scale = 1.f; }
    gemm_body(A, Wt, bias, addv, outp, Bc * Tc, Tc, scale, sa, sb);
}

// ---------------------------------------------------------------------------
// p projection + fused dpw epilogue: dpw[h][w] = 0.125*(pbv-pbu)[h].p[h][w].
// Block (bx,by) holds the full DK for 64 w-rows of head by in sa after the body.
// ---------------------------------------------------------------------------
__global__ __launch_bounds__(256) void gemm_p(
    const float* __restrict__ pos_emb, const float* __restrict__ Wpos,
    const float* __restrict__ pbu, const float* __restrict__ pbv,
    unsigned short* __restrict__ ph_b, float* __restrict__ dpw)
{
    __shared__ unsigned short sa[64 * 72];
    __shared__ unsigned short sb[64 * 72];
    gemm_body(pos_emb, Wpos, nullptr, nullptr, ph_b, Pc, Pc, 1.f, sa, sb);
    // sa still holds this block's bf16 output tile (row = w - m0, col = dk)
    const int tid = threadIdx.x;
    const int m0 = blockIdx.x * 64, h = blockIdx.y;
    if (tid < 64) {
        int w = m0 + tid;
        if (w < Pc) {
            float acc = 0.f;
            #pragma unroll
            for (int dk = 0; dk < DKc; dk++)
                acc = fmaf(pbv[h * DKc + dk] - pbu[h * DKc + dk],
                           bs2f(sa[tid * 72 + dk]), acc);
            dpw[h * Pc + w] = acc * 0.125f;
        }
    }
}

// ---------------------------------------------------------------------------
// Output projection, hi/lo split for fp32-grade accuracy. Wo split inline.
// ---------------------------------------------------------------------------
__global__ __launch_bounds__(256) void gemm_out_split(
    const unsigned short* __restrict__ Ahi,
    const unsigned short* __restrict__ Alo,
    const float* __restrict__ Wo,
    const float* __restrict__ bias,
    float* __restrict__ outp, int M)
{
    __shared__ unsigned short sah[64 * 72];
    __shared__ unsigned short sal[64 * 72];
    __shared__ unsigned short sbh[64 * 72];
    __shared__ unsigned short sbl[64 * 72];
    __shared__ float sout[64 * 68];
    const int tid = threadIdx.x;
    const int wv = tid >> 6, lane = tid & 63;
    const int c = lane & 15, g = lane >> 4;
    const int m0 = blockIdx.x * 64, n0 = blockIdx.y * 64;
    const int tb = wv * 16;

    f32x4 acc[4];
    #pragma unroll
    for (int ct = 0; ct < 4; ct++) acc[ct] = (f32x4){0.f, 0.f, 0.f, 0.f};

    for (int k0 = 0; k0 < 256; k0 += 64) {
        if (k0) __syncthreads();
        #pragma unroll
        for (int r = 0; r < 2; r++) {
            int lin = tid + 256 * r;
            int row = lin >> 3, ch = lin & 7;
            size_t asrc = (size_t)(m0 + row) * 256 + k0 + ch * 8;
            *(uint4*)&sah[row * 72 + ch * 8] = *(const uint4*)(Ahi + asrc);
            *(uint4*)&sal[row * 72 + ch * 8] = *(const uint4*)(Alo + asrc);
            float4 w0 = *(const float4*)(Wo + (size_t)(n0 + row) * 256 + k0 + ch * 8);
            float4 w1 = *(const float4*)(Wo + (size_t)(n0 + row) * 256 + k0 + ch * 8 + 4);
            float we[8] = {w0.x, w0.y, w0.z, w0.w, w1.x, w1.y, w1.z, w1.w};
            unsigned short phi[8], plo[8];
            #pragma unroll
            for (int e = 0; e < 8; e++) {
                unsigned short hi = f2bs(we[e]);
                phi[e] = hi;
                plo[e] = f2bs(we[e] - bs2f(hi));
            }
            *(uint4*)&sbh[row * 72 + ch * 8] = *(const uint4*)phi;
            *(uint4*)&sbl[row * 72 + ch * 8] = *(const uint4*)plo;
        }
        __syncthreads();
        #pragma unroll
        for (int kk = 0; kk < 2; kk++) {
            bf16x8 ah = *(const bf16x8*)&sah[(tb + c) * 72 + kk * 32 + g * 8];
            bf16x8 al = *(const bf16x8*)&sal[(tb + c) * 72 + kk * 32 + g * 8];
            #pragma unroll
            for (int ct = 0; ct < 4; ct++) {
                bf16x8 bh = *(const bf16x8*)&sbh[(ct * 16 + c) * 72 + kk * 32 + g * 8];
                bf16x8 bl = *(const bf16x8*)&sbl[(ct * 16 + c) * 72 + kk * 32 + g * 8];
                acc[ct] = __builtin_amdgcn_mfma_f32_16x16x32_bf16(ah, bh, acc[ct], 0, 0, 0);
                acc[ct] = __builtin_amdgcn_mfma_f32_16x16x32_bf16(ah, bl, acc[ct], 0, 0, 0);
                acc[ct] = __builtin_amdgcn_mfma_f32_16x16x32_bf16(al, bh, acc[ct], 0, 0, 0);
            }
        }
    }

    __syncthreads();
    #pragma unroll
    for (int ct = 0; ct < 4; ct++) {
        float b = bias[n0 + ct * 16 + c];
        #pragma unroll
        for (int r = 0; r < 4; r++)
            sout[(tb + g * 4 + r) * 68 + ct * 16 + c] = acc[ct][r] + b;
    }
    __syncthreads();
    #pragma unroll
    for (int r = 0; r < 4; r++) {
        int lin = tid + 256 * r;
        int row = lin >> 4, c4 = lin & 15;
        float4 v = *(const float4*)&sout[row * 68 + c4 * 4];
        *(float4*)&outp[(size_t)(m0 + row) * 256 + n0 + c4 * 4] = v;
    }
}

// ---------------------------------------------------------------------------
// MFMA flash attention with T14 async staging + circular P window.
// q and dpw arrive pre-scaled by 1/8, so s = AC + BD + maskadd directly.
// Per tile: write prefetched regs->LDS, barrier, ISSUE next tile's global
// loads (latency hides under compute), then AC/BD/softmax/PV.
// spw/sdpw are circular over abs&127 (window slides 64/tile -> half traffic).
// ---------------------------------------------------------------------------
__global__ __launch_bounds__(256) void attn_mfma(
    const unsigned short* __restrict__ qu,   // (B,H,T,DK) bf16, = (q+pbu)/8
    const unsigned short* __restrict__ kh,   // (B,H,T,DK) bf16
    const unsigned short* __restrict__ vh,   // (B,H,T,DK) bf16
    const unsigned short* __restrict__ ph,   // (H,P,DK)  bf16
    const float* __restrict__ dpw_g,         // (H,P), pre-scaled by 1/8
    const int*   __restrict__ mask,          // (B,T)
    unsigned short* __restrict__ xhi,        // (B,T,D) bf16 hi
    unsigned short* __restrict__ xlo)        // (B,T,D) bf16 lo
{
    __shared__ unsigned short sq[64 * 72];
    __shared__ unsigned short sk[64 * 72];
    __shared__ unsigned short svt[64 * 72];   // [dk][t^swz]
    __shared__ unsigned short sp[64 * 72];    // probs, wave-private rows
    __shared__ unsigned short spw[128 * 72];  // circular: phys = abs & 127
    __shared__ float sbdw[4][16 * 84];        // wave-private BD stripes
    __shared__ float sdpw[128];               // circular: phys = abs & 127
    __shared__ float smask[64];

    const int tid = threadIdx.x;
    const int wv = tid >> 6;
    const int lane = tid & 63;
    const int c = lane & 15, g = lane >> 4;
    const int bh = blockIdx.x, b = bh >> 2, h = bh & 3;
    const int t0 = blockIdx.y * 64;
    const int tb = wv * 16;
    const int base0 = Tc - 64 - t0;           // relbase at kt=0, >= 0

    const unsigned short* qbase = qu + ((size_t)bh * Tc + t0) * DKc;
    const unsigned short* kbase = kh + (size_t)bh * Tc * DKc;
    const unsigned short* vbase = vh + (size_t)bh * Tc * DKc;
    const unsigned short* pbase = ph + (size_t)h * Pc * DKc;

    const int srow = tid >> 3, sch = tid & 7;  // staging row/chunk (row += 32 for r=1)

    // Prologue: Q tile + P old half [base0, base0+64)
    #pragma unroll
    for (int r = 0; r < 2; r++) {
        int row = srow + r * 32;
        *(uint4*)&sq[row * 72 + sch * 8] =
            *(const uint4*)(qbase + (size_t)row * DKc + sch * 8);
        int a0 = base0 + row;
        *(uint4*)&spw[(a0 & 127) * 72 + sch * 8] =
            *(const uint4*)(pbase + (size_t)a0 * DKc + sch * 8);
    }
    if (tid < 64) sdpw[(base0 + tid) & 127] = dpw_g[h * Pc + base0 + tid];

    // async-stage registers + issue loads for tile 0
    uint4 kreg[2], vreg[2], preg[2];
    float dpwreg = 0.f; int mreg = 1;
    #pragma unroll
    for (int r = 0; r < 2; r++) {
        int row = srow + r * 32;
        kreg[r] = *(const uint4*)(kbase + (size_t)row * DKc + sch * 8);
        vreg[r] = *(const uint4*)(vbase + (size_t)row * DKc + sch * 8);
        preg[r] = *(const uint4*)(pbase + (size_t)(base0 + 64 + row) * DKc + sch * 8);
    }
    if (tid < 64) {
        dpwreg = dpw_g[h * Pc + base0 + 64 + tid];
        mreg = mask[b * Tc + tid];
    }

    f32x4 O[4];
    #pragma unroll
    for (int ct = 0; ct < 4; ct++) O[ct] = (f32x4){0.f, 0.f, 0.f, 0.f};
    float mrow[4], lrow[4];
    #pragma unroll
    for (int r = 0; r < 4; r++) { mrow[r] = -3.0e38f; lrow[r] = 0.f; }

    bf16x8 qf0, qf1;

    for (int kt = 0; kt < Tc / 64; kt++) {
        const int relb = base0 + kt * 64;
        __syncthreads();                      // prior compute done reading LDS

        // ---- write prefetched regs -> LDS
        #pragma unroll
        for (int r = 0; r < 2; r++) {
            int row = srow + r * 32;
            *(uint4*)&sk[row * 72 + sch * 8] = kreg[r];
            unsigned short el[8];
            __builtin_memcpy(el, &vreg[r], 16);
            #pragma unroll
            for (int e = 0; e < 8; e++) {
                int dk = sch * 8 + e;
                svt[dk * 72 + (row ^ ((dk >> 3) << 3))] = el[e];
            }
            *(uint4*)&spw[((relb + 64 + row) & 127) * 72 + sch * 8] = preg[r];
        }
        if (tid < 64) {
            sdpw[(relb + 64 + tid) & 127] = dpwreg;
            smask[tid] = (mreg == 0) ? -1e9f : 0.f;
        }
        __syncthreads();

        // ---- issue next tile's global loads (hide under compute below)
        if (kt < Tc / 64 - 1) {
            const int j0n = (kt + 1) * 64;
            const int relbn = relb + 64;
            #pragma unroll
            for (int r = 0; r < 2; r++) {
                int row = srow + r * 32;
                kreg[r] = *(const uint4*)(kbase + (size_t)(j0n + row) * DKc + sch * 8);
                vreg[r] = *(const uint4*)(vbase + (size_t)(j0n + row) * DKc + sch * 8);
                preg[r] = *(const uint4*)(pbase + (size_t)(relbn + 64 + row) * DKc + sch * 8);
            }
            if (tid < 64) {
                dpwreg = dpw_g[h * Pc + relbn + 64 + tid];
                mreg = mask[b * Tc + j0n + tid];
            }
        }

        if (kt == 0) {
            qf0 = *(const bf16x8*)&sq[(tb + c) * 72 + g * 8];
            qf1 = *(const bf16x8*)&sq[(tb + c) * 72 + (4 + g) * 8];
        }

        // ---- AC: 16x64 score stripe
        f32x4 sac[4];
        #pragma unroll
        for (int ct = 0; ct < 4; ct++) {
            f32x4 acc = (f32x4){0.f, 0.f, 0.f, 0.f};
            bf16x8 kf0 = *(const bf16x8*)&sk[(ct * 16 + c) * 72 + g * 8];
            bf16x8 kf1 = *(const bf16x8*)&sk[(ct * 16 + c) * 72 + (4 + g) * 8];
            acc = __builtin_amdgcn_mfma_f32_16x16x32_bf16(qf0, kf0, acc, 0, 0, 0);
            acc = __builtin_amdgcn_mfma_f32_16x16x32_bf16(qf1, kf1, acc, 0, 0, 0);
            sac[ct] = acc;
        }

        // ---- BD: 16x80 banded stripe -> wave-private LDS (+dpw folded)
        #pragma unroll
        for (int wt = 0; wt < 5; wt++) {
            f32x4 acc = (f32x4){0.f, 0.f, 0.f, 0.f};
            int wlog = (48 - tb) + wt * 16 + c;       // logical window row
            int phys = (relb + wlog) & 127;
            bf16x8 pf0 = *(const bf16x8*)&spw[phys * 72 + g * 8];
            bf16x8 pf1 = *(const bf16x8*)&spw[phys * 72 + (4 + g) * 8];
            acc = __builtin_amdgcn_mfma_f32_16x16x32_bf16(qf0, pf0, acc, 0, 0, 0);
            acc = __builtin_amdgcn_mfma_f32_16x16x32_bf16(qf1, pf1, acc, 0, 0, 0);
            float dpwv = sdpw[phys];
            #pragma unroll
            for (int r = 0; r < 4; r++)
                sbdw[wv][(g * 4 + r) * 84 + wt * 16 + c] = acc[r] + dpwv;
        }

        // ---- assemble scores: s = AC + BD[t][j-t+15] + mask (pre-scaled)
        float sreg[4][4];
        #pragma unroll
        for (int ct = 0; ct < 4; ct++) {
            float madd = smask[ct * 16 + c];
            #pragma unroll
            for (int r = 0; r < 4; r++) {
                int tt = g * 4 + r;
                int x = ct * 16 + c - tt + 15;        // in [0,78]
                sreg[ct][r] = sac[ct][r] + sbdw[wv][tt * 84 + x] + madd;
            }
        }

        // ---- online softmax
        float tmax[4], tsum[4];
        #pragma unroll
        for (int r = 0; r < 4; r++)
            tmax[r] = fmaxf(fmaxf(sreg[0][r], sreg[1][r]), fmaxf(sreg[2][r], sreg[3][r]));
        #pragma unroll
        for (int off = 1; off < 16; off <<= 1)
            #pragma unroll
            for (int r = 0; r < 4; r++)
                tmax[r] = fmaxf(tmax[r], __shfl_xor(tmax[r], off));

        float mnew[4], scl[4];
        #pragma unroll
        for (int r = 0; r < 4; r++) {
            mnew[r] = fmaxf(mrow[r], tmax[r]);
            scl[r] = __expf(mrow[r] - mnew[r]);
        }
        float pr[4][4];
        #pragma unroll
        for (int r = 0; r < 4; r++) {
            #pragma unroll
            for (int ct = 0; ct < 4; ct++)
                pr[ct][r] = __expf(sreg[ct][r] - mnew[r]);
            tsum[r] = (pr[0][r] + pr[1][r]) + (pr[2][r] + pr[3][r]);
        }
        #pragma unroll
        for (int off = 1; off < 16; off <<= 1)
            #pragma unroll
            for (int r = 0; r < 4; r++)
                tsum[r] += __shfl_xor(tsum[r], off);
        #pragma unroll
        for (int r = 0; r < 4; r++) {
            lrow[r] = lrow[r] * scl[r] + tsum[r];
            mrow[r] = mnew[r];
        }
        #pragma unroll
        for (int ct = 0; ct < 4; ct++) {
            f32x4 o = O[ct];
            o[0] *= scl[0]; o[1] *= scl[1]; o[2] *= scl[2]; o[3] *= scl[3];
            O[ct] = o;
        }

        // ---- P -> bf16 LDS (wave-private rows), then PV
        #pragma unroll
        for (int ct = 0; ct < 4; ct++)
            #pragma unroll
            for (int r = 0; r < 4; r++)
                sp[(tb + g * 4 + r) * 72 + ct * 16 + c] = f2bs(pr[ct][r]);

        #pragma unroll
        for (int js = 0; js < 2; js++) {
            bf16x8 pfrag = *(const bf16x8*)&sp[(tb + c) * 72 + (js * 4 + g) * 8];
            #pragma unroll
            for (int ct = 0; ct < 4; ct++) {
                int dk = ct * 16 + c;
                int tcol = (js * 32 + g * 8) ^ ((dk >> 3) << 3);
                bf16x8 vf = *(const bf16x8*)&svt[dk * 72 + tcol];
                O[ct] = __builtin_amdgcn_mfma_f32_16x16x32_bf16(pfrag, vf, O[ct], 0, 0, 0);
            }
        }
    }

    // ---- epilogue: normalize, write bf16 hi + lo residual
    float invl[4];
    #pragma unroll
    for (int r = 0; r < 4; r++)
        invl[r] = (lrow[r] > 0.f) ? 1.f / lrow[r] : 0.f;
    #pragma unroll
    for (int ct = 0; ct < 4; ct++)
        #pragma unroll
        for (int r = 0; r < 4; r++) {
            size_t idx = ((size_t)(b * Tc + t0 + tb + g * 4 + r)) * Dc + h * DKc + ct * 16 + c;
            float v = O[ct][r] * invl[r];
            unsigned short hi = f2bs(v);
            xhi[idx] = hi;
            xlo[idx] = f2bs(v - bs2f(hi));
        }
}

// ---------------------------------------------------------------------------
extern "C" void kernel_launch(void* const* d_in, const int* in_sizes, int n_in,
                              void* d_out, int out_size, void* d_ws, size_t ws_size,
                              hipStream_t stream) {
    const float* query   = (const float*)d_in[0];
    const float* key_    = (const float*)d_in[1];
    const float* value   = (const float*)d_in[2];
    const float* pos_emb = (const float*)d_in[3];
    const int*   mask    = (const int*)d_in[4];
    const float* Wq  = (const float*)d_in[5];
    const float* bq  = (const float*)d_in[6];
    const float* Wk  = (const float*)d_in[7];
    const float* bk  = (const float*)d_in[8];
    const float* Wv  = (const float*)d_in[9];
    const float* bv  = (const float*)d_in[10];
    const float* Wpos = (const float*)d_in[11];
    const float* pbu = (const float*)d_in[12];
    const float* pbv = (const float*)d_in[13];
    const float* Wo  = (const float*)d_in[14];
    const float* bo  = (const float*)d_in[15];
    float* out = (float*)d_out;

    // Workspace layout (~22 MB)
    const size_t NQ = (size_t)Bc * Hc * Tc * DKc;       // 2,097,152
    unsigned short* qu_b = (unsigned short*)d_ws;
    unsigned short* kh_b = qu_b + NQ;
    unsigned short* vh_b = kh_b + NQ;
    unsigned short* ph_b = vh_b + NQ;                   // 1,048,576 slot
    unsigned short* xhi  = ph_b + 1048576;
    unsigned short* xlo  = xhi + NQ;
    float* dpw = (float*)(xlo + NQ);                    // 16,380 floats

    dim3 blk(256);
    gemm_qkv<<<dim3(128, 4, 3), blk, 0, stream>>>(query, key_, value,
        Wq, bq, Wk, bk, Wv, bv, pbu, qu_b, kh_b, vh_b);
    gemm_p<<<dim3(64, 4), blk, 0, stream>>>(pos_emb, Wpos, pbu, pbv, ph_b, dpw);
    attn_mfma<<<dim3(Bc * Hc, Tc / 64), blk, 0, stream>>>(qu_b, kh_b, vh_b, ph_b, dpw, mask, xhi, xlo);
    gemm_out_split<<<dim3(128, 4), blk, 0, stream>>>(xhi, xlo, Wo, bo, out, Bc * Tc);
}

// Round 7
// 223.845 us; speedup vs baseline: 4.3976x; 1.0980x over previous
//
#include <hip/hip_runtime.h>
#include <hip/hip_bf16.h>
#include <string.h>

// Problem constants (reference: B=4, T=2048, D=256, H=4, DK=64, P=2T-1)
#define Bc 4
#define Tc 2048
#define Dc 256
#define Hc 4
#define DKc 64
#define Pc 4095

typedef short bf16x8 __attribute__((ext_vector_type(8)));
typedef float f32x4 __attribute__((ext_vector_type(4)));

__device__ __forceinline__ unsigned short f2bs(float x) {
    __bf16 b = (__bf16)x;                       // RNE convert
    return __builtin_bit_cast(unsigned short, b);
}
__device__ __forceinline__ float bs2f(unsigned short u) {
    unsigned int x = ((unsigned int)u) << 16;
    return __builtin_bit_cast(float, x);
}

// ---------------------------------------------------------------------------
// Shared bf16-MFMA GEMM body: out = bf16( scale * (A @ W^T + bias + addv) ),
// head-split (b,h,t,dk). 64x64 tile, BK=64, 4 waves, 8 MFMA/wave/K-step.
// LDS rows padded to 72 shorts (144B) -> conflict-free b128 reads/writes.
// ---------------------------------------------------------------------------
__device__ __forceinline__ void gemm_body(
    const float* __restrict__ A, const float* __restrict__ Wt,
    const float* __restrict__ bias, const float* __restrict__ addv,
    unsigned short* __restrict__ outp, int M, int Tdim, float scale,
    unsigned short* sa, unsigned short* sb)
{
    const int tid = threadIdx.x;
    const int wv = tid >> 6, lane = tid & 63;
    const int c = lane & 15, g = lane >> 4;
    const int m0 = blockIdx.x * 64, n0 = blockIdx.y * 64;
    const int tb = wv * 16;

    f32x4 acc[4];
    #pragma unroll
    for (int ct = 0; ct < 4; ct++) acc[ct] = (f32x4){0.f, 0.f, 0.f, 0.f};

    for (int k0 = 0; k0 < 256; k0 += 64) {
        if (k0) __syncthreads();
        #pragma unroll
        for (int r = 0; r < 2; r++) {
            int lin = tid + 256 * r;
            int row = lin >> 3, ch = lin & 7;
            int gm = m0 + row;
            float4 f0, f1;
            if (gm < M) {
                f0 = *(const float4*)(A + (size_t)gm * 256 + k0 + ch * 8);
                f1 = *(const float4*)(A + (size_t)gm * 256 + k0 + ch * 8 + 4);
            } else {
                f0 = make_float4(0.f, 0.f, 0.f, 0.f); f1 = f0;
            }
            unsigned short pa[8] = {f2bs(f0.x), f2bs(f0.y), f2bs(f0.z), f2bs(f0.w),
                                    f2bs(f1.x), f2bs(f1.y), f2bs(f1.z), f2bs(f1.w)};
            *(uint4*)&sa[row * 72 + ch * 8] = *(const uint4*)pa;

            float4 w0 = *(const float4*)(Wt + (size_t)(n0 + row) * 256 + k0 + ch * 8);
            float4 w1 = *(const float4*)(Wt + (size_t)(n0 + row) * 256 + k0 + ch * 8 + 4);
            unsigned short pb[8] = {f2bs(w0.x), f2bs(w0.y), f2bs(w0.z), f2bs(w0.w),
                                    f2bs(w1.x), f2bs(w1.y), f2bs(w1.z), f2bs(w1.w)};
            *(uint4*)&sb[row * 72 + ch * 8] = *(const uint4*)pb;
        }
        __syncthreads();
        #pragma unroll
        for (int kk = 0; kk < 2; kk++) {
            bf16x8 af = *(const bf16x8*)&sa[(tb + c) * 72 + kk * 32 + g * 8];
            #pragma unroll
            for (int ct = 0; ct < 4; ct++) {
                bf16x8 bf = *(const bf16x8*)&sb[(ct * 16 + c) * 72 + kk * 32 + g * 8];
                acc[ct] = __builtin_amdgcn_mfma_f32_16x16x32_bf16(af, bf, acc[ct], 0, 0, 0);
            }
        }
    }

    __syncthreads();
    #pragma unroll
    for (int ct = 0; ct < 4; ct++) {
        int n = n0 + ct * 16 + c;
        float badd = (bias ? bias[n] : 0.f) + (addv ? addv[n] : 0.f);
        #pragma unroll
        for (int r = 0; r < 4; r++)
            sa[(tb + g * 4 + r) * 72 + ct * 16 + c] = f2bs((acc[ct][r] + badd) * scale);
    }
    __syncthreads();
    const int hh = n0 >> 6;
    #pragma unroll
    for (int r = 0; r < 2; r++) {
        int lin = tid + 256 * r;
        int row = lin >> 3, ch = lin & 7;
        int gm = m0 + row;
        if (gm >= M) continue;
        int bb = gm / Tdim, t = gm - bb * Tdim;
        size_t oidx = ((size_t)(bb * Hc + hh) * Tdim + t) * DKc + ch * 8;
        *(uint4*)&outp[oidx] = *(const uint4*)&sa[row * 72 + ch * 8];
    }
}

// ---------------------------------------------------------------------------
// Fused q/k/v projections (blockIdx.z selects). q is pre-scaled by 1/8.
// ---------------------------------------------------------------------------
__global__ __launch_bounds__(256) void gemm_qkv(
    const float* __restrict__ q, const float* __restrict__ k, const float* __restrict__ v,
    const float* __restrict__ Wq, const float* __restrict__ bq,
    const float* __restrict__ Wk, const float* __restrict__ bk,
    const float* __restrict__ Wv, const float* __restrict__ bv,
    const float* __restrict__ pbu,
    unsigned short* __restrict__ qo, unsigned short* __restrict__ ko,
    unsigned short* __restrict__ vo)
{
    __shared__ unsigned short sa[64 * 72];
    __shared__ unsigned short sb[64 * 72];
    const float *A, *Wt, *bias, *addv; unsigned short* outp; float scale;
    if (blockIdx.z == 0)      { A = q; Wt = Wq; bias = bq; addv = pbu;    outp = qo; scale = 0.125f; }
    else if (blockIdx.z == 1) { A = k; Wt = Wk; bias = bk; addv = nullptr; outp = ko; scale = 1.f; }
    else                      { A = v; Wt = Wv; bias = bv; addv = nullptr; outp = vo; scale = 1.f; }
    gemm_body(A, Wt, bias, addv, outp, Bc * Tc, Tc, scale, sa, sb);
}

// ---------------------------------------------------------------------------
// p projection + fused dpw epilogue: dpw[h][w] = 0.125*(pbv-pbu)[h].p[h][w].
// ---------------------------------------------------------------------------
__global__ __launch_bounds__(256) void gemm_p(
    const float* __restrict__ pos_emb, const float* __restrict__ Wpos,
    const float* __restrict__ pbu, const float* __restrict__ pbv,
    unsigned short* __restrict__ ph_b, float* __restrict__ dpw)
{
    __shared__ unsigned short sa[64 * 72];
    __shared__ unsigned short sb[64 * 72];
    gemm_body(pos_emb, Wpos, nullptr, nullptr, ph_b, Pc, Pc, 1.f, sa, sb);
    // sa still holds this block's bf16 output tile (row = w - m0, col = dk)
    const int tid = threadIdx.x;
    const int m0 = blockIdx.x * 64, h = blockIdx.y;
    if (tid < 64) {
        int w = m0 + tid;
        if (w < Pc) {
            float acc = 0.f;
            #pragma unroll
            for (int dk = 0; dk < DKc; dk++)
                acc = fmaf(pbv[h * DKc + dk] - pbu[h * DKc + dk],
                           bs2f(sa[tid * 72 + dk]), acc);
            dpw[h * Pc + w] = acc * 0.125f;
        }
    }
}

// ---------------------------------------------------------------------------
// Output projection, hi/lo split for fp32-grade accuracy. Wo split inline.
// ---------------------------------------------------------------------------
__global__ __launch_bounds__(256) void gemm_out_split(
    const unsigned short* __restrict__ Ahi,
    const unsigned short* __restrict__ Alo,
    const float* __restrict__ Wo,
    const float* __restrict__ bias,
    float* __restrict__ outp, int M)
{
    __shared__ unsigned short sah[64 * 72];
    __shared__ unsigned short sal[64 * 72];
    __shared__ unsigned short sbh[64 * 72];
    __shared__ unsigned short sbl[64 * 72];
    __shared__ float sout[64 * 68];
    const int tid = threadIdx.x;
    const int wv = tid >> 6, lane = tid & 63;
    const int c = lane & 15, g = lane >> 4;
    const int m0 = blockIdx.x * 64, n0 = blockIdx.y * 64;
    const int tb = wv * 16;

    f32x4 acc[4];
    #pragma unroll
    for (int ct = 0; ct < 4; ct++) acc[ct] = (f32x4){0.f, 0.f, 0.f, 0.f};

    for (int k0 = 0; k0 < 256; k0 += 64) {
        if (k0) __syncthreads();
        #pragma unroll
        for (int r = 0; r < 2; r++) {
            int lin = tid + 256 * r;
            int row = lin >> 3, ch = lin & 7;
            size_t asrc = (size_t)(m0 + row) * 256 + k0 + ch * 8;
            *(uint4*)&sah[row * 72 + ch * 8] = *(const uint4*)(Ahi + asrc);
            *(uint4*)&sal[row * 72 + ch * 8] = *(const uint4*)(Alo + asrc);
            float4 w0 = *(const float4*)(Wo + (size_t)(n0 + row) * 256 + k0 + ch * 8);
            float4 w1 = *(const float4*)(Wo + (size_t)(n0 + row) * 256 + k0 + ch * 8 + 4);
            float we[8] = {w0.x, w0.y, w0.z, w0.w, w1.x, w1.y, w1.z, w1.w};
            unsigned short phi[8], plo[8];
            #pragma unroll
            for (int e = 0; e < 8; e++) {
                unsigned short hi = f2bs(we[e]);
                phi[e] = hi;
                plo[e] = f2bs(we[e] - bs2f(hi));
            }
            *(uint4*)&sbh[row * 72 + ch * 8] = *(const uint4*)phi;
            *(uint4*)&sbl[row * 72 + ch * 8] = *(const uint4*)plo;
        }
        __syncthreads();
        #pragma unroll
        for (int kk = 0; kk < 2; kk++) {
            bf16x8 ah = *(const bf16x8*)&sah[(tb + c) * 72 + kk * 32 + g * 8];
            bf16x8 al = *(const bf16x8*)&sal[(tb + c) * 72 + kk * 32 + g * 8];
            #pragma unroll
            for (int ct = 0; ct < 4; ct++) {
                bf16x8 bh = *(const bf16x8*)&sbh[(ct * 16 + c) * 72 + kk * 32 + g * 8];
                bf16x8 bl = *(const bf16x8*)&sbl[(ct * 16 + c) * 72 + kk * 32 + g * 8];
                acc[ct] = __builtin_amdgcn_mfma_f32_16x16x32_bf16(ah, bh, acc[ct], 0, 0, 0);
                acc[ct] = __builtin_amdgcn_mfma_f32_16x16x32_bf16(ah, bl, acc[ct], 0, 0, 0);
                acc[ct] = __builtin_amdgcn_mfma_f32_16x16x32_bf16(al, bh, acc[ct], 0, 0, 0);
            }
        }
    }

    __syncthreads();
    #pragma unroll
    for (int ct = 0; ct < 4; ct++) {
        float b = bias[n0 + ct * 16 + c];
        #pragma unroll
        for (int r = 0; r < 4; r++)
            sout[(tb + g * 4 + r) * 68 + ct * 16 + c] = acc[ct][r] + b;
    }
    __syncthreads();
    #pragma unroll
    for (int r = 0; r < 4; r++) {
        int lin = tid + 256 * r;
        int row = lin >> 4, c4 = lin & 15;
        float4 v = *(const float4*)&sout[row * 68 + c4 * 4];
        *(float4*)&outp[(size_t)(m0 + row) * 256 + n0 + c4 * 4] = v;
    }
}

// ---------------------------------------------------------------------------
// MFMA flash attention, QT=128: 512 threads = 8 waves, each wave owns 16
// q-rows. One block per CU (grid 16x16 = 256 = #CUs). K/V/P staged ONCE per
// CU per tile (vs 2x at QT=64) -> staging work & L2 refetch halve. Direct
// global->LDS staging (round-4 style; reg-prefetch regressed in round 5).
// Circular 256-row P window (stage 64 new rows/tile), clamped sources.
// q and dpw pre-scaled by 1/8. LDS 133.3 KB -> 1 block/CU.
// ---------------------------------------------------------------------------
__global__ __launch_bounds__(512) void attn_mfma(
    const unsigned short* __restrict__ qu,   // (B,H,T,DK) bf16, = (q+pbu)/8
    const unsigned short* __restrict__ kh,   // (B,H,T,DK) bf16
    const unsigned short* __restrict__ vh,   // (B,H,T,DK) bf16
    const unsigned short* __restrict__ ph,   // (H,P,DK)  bf16
    const float* __restrict__ dpw_g,         // (H,P), pre-scaled by 1/8
    const int*   __restrict__ mask,          // (B,T)
    unsigned short* __restrict__ xhi,        // (B,T,D) bf16 hi
    unsigned short* __restrict__ xlo)        // (B,T,D) bf16 lo
{
    __shared__ unsigned short sq[128 * 72];   // 18.4 KB
    __shared__ unsigned short sk[64 * 72];    //  9.2 KB
    __shared__ unsigned short svt[64 * 72];   //  9.2 KB  [dk][t^swz]
    __shared__ unsigned short sp[128 * 72];   // 18.4 KB  probs, wave-private rows
    __shared__ unsigned short spw[256 * 72];  // 36.9 KB  circular: phys = abs & 255
    __shared__ float sbdw[8][16 * 84];        // 43.0 KB  wave-private BD stripes
    __shared__ float sdpw[256];               // circular
    __shared__ float smask[64];

    const int tid = threadIdx.x;
    const int wv = tid >> 6;
    const int lane = tid & 63;
    const int c = lane & 15, g = lane >> 4;
    const int bh = blockIdx.x, b = bh >> 2, h = bh & 3;
    const int t0 = blockIdx.y * 128;
    const int tb = wv * 16;
    const int base0 = Tc - 128 - t0;          // window base at kt=0, >= 0

    const unsigned short* qbase = qu + ((size_t)bh * Tc + t0) * DKc;
    const unsigned short* kbase = kh + (size_t)bh * Tc * DKc;
    const unsigned short* vbase = vh + (size_t)bh * Tc * DKc;
    const unsigned short* pbase = ph + (size_t)h * Pc * DKc;

    const int srow = tid >> 3, sch = tid & 7;   // [0,64) x [0,8)

    // Prologue: Q tile (128 rows) + P window's first 128 rows
    #pragma unroll
    for (int r = 0; r < 2; r++) {
        int lin = tid + 512 * r;
        int row = lin >> 3, ch = lin & 7;
        *(uint4*)&sq[row * 72 + ch * 8] =
            *(const uint4*)(qbase + (size_t)row * DKc + ch * 8);
        int a0 = base0 + row;                  // <= 2047, in range
        *(uint4*)&spw[(a0 & 255) * 72 + ch * 8] =
            *(const uint4*)(pbase + (size_t)a0 * DKc + ch * 8);
    }
    if (tid < 128) sdpw[(base0 + tid) & 255] = dpw_g[h * Pc + base0 + tid];

    f32x4 O[4];
    #pragma unroll
    for (int ct = 0; ct < 4; ct++) O[ct] = (f32x4){0.f, 0.f, 0.f, 0.f};
    float mrow[4], lrow[4];
    #pragma unroll
    for (int r = 0; r < 4; r++) { mrow[r] = -3.0e38f; lrow[r] = 0.f; }

    bf16x8 qf0, qf1;

    for (int kt = 0; kt < Tc / 64; kt++) {
        const int j0 = kt * 64;
        const int relb = base0 + kt * 64;
        __syncthreads();                       // prior compute done reading LDS

        // ---- direct staging: K, V^T, P (64 new circular rows), dpw, mask
        *(uint4*)&sk[srow * 72 + sch * 8] =
            *(const uint4*)(kbase + (size_t)(j0 + srow) * DKc + sch * 8);
        {
            uint4 raw = *(const uint4*)(vbase + (size_t)(j0 + srow) * DKc + sch * 8);
            unsigned short el[8];
            __builtin_memcpy(el, &raw, 16);
            #pragma unroll
            for (int e = 0; e < 8; e++) {
                int dk = sch * 8 + e;
                svt[dk * 72 + (srow ^ ((dk >> 3) << 3))] = el[e];
            }
        }
        {
            int pabs = relb + 128 + srow;
            int psrc = pabs <= Pc - 1 ? pabs : Pc - 1;   // clamp source
            *(uint4*)&spw[(pabs & 255) * 72 + sch * 8] =
                *(const uint4*)(pbase + (size_t)psrc * DKc + sch * 8);
        }
        if (tid < 64) {
            int da = relb + 128 + tid;
            sdpw[da & 255] = dpw_g[h * Pc + (da <= Pc - 1 ? da : Pc - 1)];
            smask[tid] = (mask[b * Tc + j0 + tid] == 0) ? -1e9f : 0.f;
        }
        __syncthreads();

        if (kt == 0) {
            qf0 = *(const bf16x8*)&sq[(tb + c) * 72 + g * 8];
            qf1 = *(const bf16x8*)&sq[(tb + c) * 72 + (4 + g) * 8];
        }

        __builtin_amdgcn_s_setprio(1);
        // ---- AC: 16x64 score stripe
        f32x4 sac[4];
        #pragma unroll
        for (int ct = 0; ct < 4; ct++) {
            f32x4 acc = (f32x4){0.f, 0.f, 0.f, 0.f};
            bf16x8 kf0 = *(const bf16x8*)&sk[(ct * 16 + c) * 72 + g * 8];
            bf16x8 kf1 = *(const bf16x8*)&sk[(ct * 16 + c) * 72 + (4 + g) * 8];
            acc = __builtin_amdgcn_mfma_f32_16x16x32_bf16(qf0, kf0, acc, 0, 0, 0);
            acc = __builtin_amdgcn_mfma_f32_16x16x32_bf16(qf1, kf1, acc, 0, 0, 0);
            sac[ct] = acc;
        }

        // ---- BD: 16x80 banded stripe -> wave-private LDS (+dpw folded)
        const int wstart = 112 - tb;
        #pragma unroll
        for (int wt = 0; wt < 5; wt++) {
            f32x4 acc = (f32x4){0.f, 0.f, 0.f, 0.f};
            int plog = wstart + wt * 16 + c;          // [0, 191]
            int phys = (relb + plog) & 255;
            bf16x8 pf0 = *(const bf16x8*)&spw[phys * 72 + g * 8];
            bf16x8 pf1 = *(const bf16x8*)&spw[phys * 72 + (4 + g) * 8];
            acc = __builtin_amdgcn_mfma_f32_16x16x32_bf16(qf0, pf0, acc, 0, 0, 0);
            acc = __builtin_amdgcn_mfma_f32_16x16x32_bf16(qf1, pf1, acc, 0, 0, 0);
            float dpwv = sdpw[phys];
            #pragma unroll
            for (int r = 0; r < 4; r++)
                sbdw[wv][(g * 4 + r) * 84 + wt * 16 + c] = acc[r] + dpwv;
        }
        __builtin_amdgcn_s_setprio(0);

        // ---- assemble scores: s = AC + BD[t][j-t+15] + mask (pre-scaled)
        float sreg[4][4];
        #pragma unroll
        for (int ct = 0; ct < 4; ct++) {
            float madd = smask[ct * 16 + c];
            #pragma unroll
            for (int r = 0; r < 4; r++) {
                int tt = g * 4 + r;
                int x = ct * 16 + c - tt + 15;        // in [0,78]
                sreg[ct][r] = sac[ct][r] + sbdw[wv][tt * 84 + x] + madd;
            }
        }

        // ---- online softmax
        float tmax[4], tsum[4];
        #pragma unroll
        for (int r = 0; r < 4; r++)
            tmax[r] = fmaxf(fmaxf(sreg[0][r], sreg[1][r]), fmaxf(sreg[2][r], sreg[3][r]));
        #pragma unroll
        for (int off = 1; off < 16; off <<= 1)
            #pragma unroll
            for (int r = 0; r < 4; r++)
                tmax[r] = fmaxf(tmax[r], __shfl_xor(tmax[r], off));

        float mnew[4], scl[4];
        #pragma unroll
        for (int r = 0; r < 4; r++) {
            mnew[r] = fmaxf(mrow[r], tmax[r]);
            scl[r] = __expf(mrow[r] - mnew[r]);
        }
        float pr[4][4];
        #pragma unroll
        for (int r = 0; r < 4; r++) {
            #pragma unroll
            for (int ct = 0; ct < 4; ct++)
                pr[ct][r] = __expf(sreg[ct][r] - mnew[r]);
            tsum[r] = (pr[0][r] + pr[1][r]) + (pr[2][r] + pr[3][r]);
        }
        #pragma unroll
        for (int off = 1; off < 16; off <<= 1)
            #pragma unroll
            for (int r = 0; r < 4; r++)
                tsum[r] += __shfl_xor(tsum[r], off);
        #pragma unroll
        for (int r = 0; r < 4; r++) {
            lrow[r] = lrow[r] * scl[r] + tsum[r];
            mrow[r] = mnew[r];
        }
        #pragma unroll
        for (int ct = 0; ct < 4; ct++) {
            f32x4 o = O[ct];
            o[0] *= scl[0]; o[1] *= scl[1]; o[2] *= scl[2]; o[3] *= scl[3];
            O[ct] = o;
        }

        // ---- P -> bf16 LDS (wave-private rows), then PV
        #pragma unroll
        for (int ct = 0; ct < 4; ct++)
            #pragma unroll
            for (int r = 0; r < 4; r++)
                sp[(tb + g * 4 + r) * 72 + ct * 16 + c] = f2bs(pr[ct][r]);

        __builtin_amdgcn_s_setprio(1);
        #pragma unroll
        for (int js = 0; js < 2; js++) {
            bf16x8 pfrag = *(const bf16x8*)&sp[(tb + c) * 72 + (js * 4 + g) * 8];
            #pragma unroll
            for (int ct = 0; ct < 4; ct++) {
                int dk = ct * 16 + c;
                int tcol = (js * 32 + g * 8) ^ ((dk >> 3) << 3);
                bf16x8 vf = *(const bf16x8*)&svt[dk * 72 + tcol];
                O[ct] = __builtin_amdgcn_mfma_f32_16x16x32_bf16(pfrag, vf, O[ct], 0, 0, 0);
            }
        }
        __builtin_amdgcn_s_setprio(0);
    }

    // ---- epilogue: normalize, write bf16 hi + lo residual
    float invl[4];
    #pragma unroll
    for (int r = 0; r < 4; r++)
        invl[r] = (lrow[r] > 0.f) ? 1.f / lrow[r] : 0.f;
    #pragma unroll
    for (int ct = 0; ct < 4; ct++)
        #pragma unroll
        for (int r = 0; r < 4; r++) {
            size_t idx = ((size_t)(b * Tc + t0 + tb + g * 4 + r)) * Dc + h * DKc + ct * 16 + c;
            float v = O[ct][r] * invl[r];
            unsigned short hi = f2bs(v);
            xhi[idx] = hi;
            xlo[idx] = f2bs(v - bs2f(hi));
        }
}

// ---------------------------------------------------------------------------
extern "C" void kernel_launch(void* const* d_in, const int* in_sizes, int n_in,
                              void* d_out, int out_size, void* d_ws, size_t ws_size,
                              hipStream_t stream) {
    const float* query   = (const float*)d_in[0];
    const float* key_    = (const float*)d_in[1];
    const float* value   = (const float*)d_in[2];
    const float* pos_emb = (const float*)d_in[3];
    const int*   mask    = (const int*)d_in[4];
    const float* Wq  = (const float*)d_in[5];
    const float* bq  = (const float*)d_in[6];
    const float* Wk  = (const float*)d_in[7];
    const float* bk  = (const float*)d_in[8];
    const float* Wv  = (const float*)d_in[9];
    const float* bv  = (const float*)d_in[10];
    const float* Wpos = (const float*)d_in[11];
    const float* pbu = (const float*)d_in[12];
    const float* pbv = (const float*)d_in[13];
    const float* Wo  = (const float*)d_in[14];
    const float* bo  = (const float*)d_in[15];
    float* out = (float*)d_out;

    // Workspace layout (~22 MB)
    const size_t NQ = (size_t)Bc * Hc * Tc * DKc;       // 2,097,152
    unsigned short* qu_b = (unsigned short*)d_ws;
    unsigned short* kh_b = qu_b + NQ;
    unsigned short* vh_b = kh_b + NQ;
    unsigned short* ph_b = vh_b + NQ;                   // 1,048,576 slot
    unsigned short* xhi  = ph_b + 1048576;
    unsigned short* xlo  = xhi + NQ;
    float* dpw = (float*)(xlo + NQ);                    // 16,380 floats

    gemm_qkv<<<dim3(128, 4, 3), dim3(256), 0, stream>>>(query, key_, value,
        Wq, bq, Wk, bk, Wv, bv, pbu, qu_b, kh_b, vh_b);
    gemm_p<<<dim3(64, 4), dim3(256), 0, stream>>>(pos_emb, Wpos, pbu, pbv, ph_b, dpw);
    attn_mfma<<<dim3(Bc * Hc, Tc / 128), dim3(512), 0, stream>>>(
        qu_b, kh_b, vh_b, ph_b, dpw, mask, xhi, xlo);
    gemm_out_split<<<dim3(128, 4), dim3(256), 0, stream>>>(xhi, xlo, Wo, bo, out, Bc * Tc);
}

// Round 8
// 211.522 us; speedup vs baseline: 4.6538x; 1.0583x over previous
//
#include <hip/hip_runtime.h>
#include <hip/hip_bf16.h>
#include <string.h>

// Problem constants (reference: B=4, T=2048, D=256, H=4, DK=64, P=2T-1)
#define Bc 4
#define Tc 2048
#define Dc 256
#define Hc 4
#define DKc 64
#define Pc 4095

typedef short bf16x8 __attribute__((ext_vector_type(8)));
typedef float f32x4 __attribute__((ext_vector_type(4)));

__device__ __forceinline__ unsigned short f2bs(float x) {
    __bf16 b = (__bf16)x;                       // RNE convert
    return __builtin_bit_cast(unsigned short, b);
}
__device__ __forceinline__ float bs2f(unsigned short u) {
    unsigned int x = ((unsigned int)u) << 16;
    return __builtin_bit_cast(float, x);
}

// ---------------------------------------------------------------------------
// Shared bf16-MFMA GEMM body: out = bf16( scale * (A @ W^T + bias + addv) ),
// head-split (b,h,t,dk). 64x64 tile, BK=64, 4 waves, 8 MFMA/wave/K-step.
// LDS rows padded to 72 shorts (144B) -> conflict-free b128 reads/writes.
// ---------------------------------------------------------------------------
__device__ __forceinline__ void gemm_body(
    const float* __restrict__ A, const float* __restrict__ Wt,
    const float* __restrict__ bias, const float* __restrict__ addv,
    unsigned short* __restrict__ outp, int M, int Tdim, float scale,
    unsigned short* sa, unsigned short* sb)
{
    const int tid = threadIdx.x;
    const int wv = tid >> 6, lane = tid & 63;
    const int c = lane & 15, g = lane >> 4;
    const int m0 = blockIdx.x * 64, n0 = blockIdx.y * 64;
    const int tb = wv * 16;

    f32x4 acc[4];
    #pragma unroll
    for (int ct = 0; ct < 4; ct++) acc[ct] = (f32x4){0.f, 0.f, 0.f, 0.f};

    for (int k0 = 0; k0 < 256; k0 += 64) {
        if (k0) __syncthreads();
        #pragma unroll
        for (int r = 0; r < 2; r++) {
            int lin = tid + 256 * r;
            int row = lin >> 3, ch = lin & 7;
            int gm = m0 + row;
            float4 f0, f1;
            if (gm < M) {
                f0 = *(const float4*)(A + (size_t)gm * 256 + k0 + ch * 8);
                f1 = *(const float4*)(A + (size_t)gm * 256 + k0 + ch * 8 + 4);
            } else {
                f0 = make_float4(0.f, 0.f, 0.f, 0.f); f1 = f0;
            }
            unsigned short pa[8] = {f2bs(f0.x), f2bs(f0.y), f2bs(f0.z), f2bs(f0.w),
                                    f2bs(f1.x), f2bs(f1.y), f2bs(f1.z), f2bs(f1.w)};
            *(uint4*)&sa[row * 72 + ch * 8] = *(const uint4*)pa;

            float4 w0 = *(const float4*)(Wt + (size_t)(n0 + row) * 256 + k0 + ch * 8);
            float4 w1 = *(const float4*)(Wt + (size_t)(n0 + row) * 256 + k0 + ch * 8 + 4);
            unsigned short pb[8] = {f2bs(w0.x), f2bs(w0.y), f2bs(w0.z), f2bs(w0.w),
                                    f2bs(w1.x), f2bs(w1.y), f2bs(w1.z), f2bs(w1.w)};
            *(uint4*)&sb[row * 72 + ch * 8] = *(const uint4*)pb;
        }
        __syncthreads();
        #pragma unroll
        for (int kk = 0; kk < 2; kk++) {
            bf16x8 af = *(const bf16x8*)&sa[(tb + c) * 72 + kk * 32 + g * 8];
            #pragma unroll
            for (int ct = 0; ct < 4; ct++) {
                bf16x8 bf = *(const bf16x8*)&sb[(ct * 16 + c) * 72 + kk * 32 + g * 8];
                acc[ct] = __builtin_amdgcn_mfma_f32_16x16x32_bf16(af, bf, acc[ct], 0, 0, 0);
            }
        }
    }

    __syncthreads();
    #pragma unroll
    for (int ct = 0; ct < 4; ct++) {
        int n = n0 + ct * 16 + c;
        float badd = (bias ? bias[n] : 0.f) + (addv ? addv[n] : 0.f);
        #pragma unroll
        for (int r = 0; r < 4; r++)
            sa[(tb + g * 4 + r) * 72 + ct * 16 + c] = f2bs((acc[ct][r] + badd) * scale);
    }
    __syncthreads();
    const int hh = n0 >> 6;
    #pragma unroll
    for (int r = 0; r < 2; r++) {
        int lin = tid + 256 * r;
        int row = lin >> 3, ch = lin & 7;
        int gm = m0 + row;
        if (gm >= M) continue;
        int bb = gm / Tdim, t = gm - bb * Tdim;
        size_t oidx = ((size_t)(bb * Hc + hh) * Tdim + t) * DKc + ch * 8;
        *(uint4*)&outp[oidx] = *(const uint4*)&sa[row * 72 + ch * 8];
    }
}

// ---------------------------------------------------------------------------
// Fused q/k/v projections (blockIdx.z selects). q is pre-scaled by 1/8.
// ---------------------------------------------------------------------------
__global__ __launch_bounds__(256) void gemm_qkv(
    const float* __restrict__ q, const float* __restrict__ k, const float* __restrict__ v,
    const float* __restrict__ Wq, const float* __restrict__ bq,
    const float* __restrict__ Wk, const float* __restrict__ bk,
    const float* __restrict__ Wv, const float* __restrict__ bv,
    const float* __restrict__ pbu,
    unsigned short* __restrict__ qo, unsigned short* __restrict__ ko,
    unsigned short* __restrict__ vo)
{
    __shared__ unsigned short sa[64 * 72];
    __shared__ unsigned short sb[64 * 72];
    const float *A, *Wt, *bias, *addv; unsigned short* outp; float scale;
    if (blockIdx.z == 0)      { A = q; Wt = Wq; bias = bq; addv = pbu;    outp = qo; scale = 0.125f; }
    else if (blockIdx.z == 1) { A = k; Wt = Wk; bias = bk; addv = nullptr; outp = ko; scale = 1.f; }
    else                      { A = v; Wt = Wv; bias = bv; addv = nullptr; outp = vo; scale = 1.f; }
    gemm_body(A, Wt, bias, addv, outp, Bc * Tc, Tc, scale, sa, sb);
}

// ---------------------------------------------------------------------------
// p projection + fused dpw epilogue: dpw[h][w] = 0.125*(pbv-pbu)[h].p[h][w].
// ---------------------------------------------------------------------------
__global__ __launch_bounds__(256) void gemm_p(
    const float* __restrict__ pos_emb, const float* __restrict__ Wpos,
    const float* __restrict__ pbu, const float* __restrict__ pbv,
    unsigned short* __restrict__ ph_b, float* __restrict__ dpw)
{
    __shared__ unsigned short sa[64 * 72];
    __shared__ unsigned short sb[64 * 72];
    gemm_body(pos_emb, Wpos, nullptr, nullptr, ph_b, Pc, Pc, 1.f, sa, sb);
    // sa still holds this block's bf16 output tile (row = w - m0, col = dk)
    const int tid = threadIdx.x;
    const int m0 = blockIdx.x * 64, h = blockIdx.y;
    if (tid < 64) {
        int w = m0 + tid;
        if (w < Pc) {
            float acc = 0.f;
            #pragma unroll
            for (int dk = 0; dk < DKc; dk++)
                acc = fmaf(pbv[h * DKc + dk] - pbu[h * DKc + dk],
                           bs2f(sa[tid * 72 + dk]), acc);
            dpw[h * Pc + w] = acc * 0.125f;
        }
    }
}

// ---------------------------------------------------------------------------
// Output projection, hi/lo split for fp32-grade accuracy. Wo split inline.
// ---------------------------------------------------------------------------
__global__ __launch_bounds__(256) void gemm_out_split(
    const unsigned short* __restrict__ Ahi,
    const unsigned short* __restrict__ Alo,
    const float* __restrict__ Wo,
    const float* __restrict__ bias,
    float* __restrict__ outp, int M)
{
    __shared__ unsigned short sah[64 * 72];
    __shared__ unsigned short sal[64 * 72];
    __shared__ unsigned short sbh[64 * 72];
    __shared__ unsigned short sbl[64 * 72];
    __shared__ float sout[64 * 68];
    const int tid = threadIdx.x;
    const int wv = tid >> 6, lane = tid & 63;
    const int c = lane & 15, g = lane >> 4;
    const int m0 = blockIdx.x * 64, n0 = blockIdx.y * 64;
    const int tb = wv * 16;

    f32x4 acc[4];
    #pragma unroll
    for (int ct = 0; ct < 4; ct++) acc[ct] = (f32x4){0.f, 0.f, 0.f, 0.f};

    for (int k0 = 0; k0 < 256; k0 += 64) {
        if (k0) __syncthreads();
        #pragma unroll
        for (int r = 0; r < 2; r++) {
            int lin = tid + 256 * r;
            int row = lin >> 3, ch = lin & 7;
            size_t asrc = (size_t)(m0 + row) * 256 + k0 + ch * 8;
            *(uint4*)&sah[row * 72 + ch * 8] = *(const uint4*)(Ahi + asrc);
            *(uint4*)&sal[row * 72 + ch * 8] = *(const uint4*)(Alo + asrc);
            float4 w0 = *(const float4*)(Wo + (size_t)(n0 + row) * 256 + k0 + ch * 8);
            float4 w1 = *(const float4*)(Wo + (size_t)(n0 + row) * 256 + k0 + ch * 8 + 4);
            float we[8] = {w0.x, w0.y, w0.z, w0.w, w1.x, w1.y, w1.z, w1.w};
            unsigned short phi[8], plo[8];
            #pragma unroll
            for (int e = 0; e < 8; e++) {
                unsigned short hi = f2bs(we[e]);
                phi[e] = hi;
                plo[e] = f2bs(we[e] - bs2f(hi));
            }
            *(uint4*)&sbh[row * 72 + ch * 8] = *(const uint4*)phi;
            *(uint4*)&sbl[row * 72 + ch * 8] = *(const uint4*)plo;
        }
        __syncthreads();
        #pragma unroll
        for (int kk = 0; kk < 2; kk++) {
            bf16x8 ah = *(const bf16x8*)&sah[(tb + c) * 72 + kk * 32 + g * 8];
            bf16x8 al = *(const bf16x8*)&sal[(tb + c) * 72 + kk * 32 + g * 8];
            #pragma unroll
            for (int ct = 0; ct < 4; ct++) {
                bf16x8 bh = *(const bf16x8*)&sbh[(ct * 16 + c) * 72 + kk * 32 + g * 8];
                bf16x8 bl = *(const bf16x8*)&sbl[(ct * 16 + c) * 72 + kk * 32 + g * 8];
                acc[ct] = __builtin_amdgcn_mfma_f32_16x16x32_bf16(ah, bh, acc[ct], 0, 0, 0);
                acc[ct] = __builtin_amdgcn_mfma_f32_16x16x32_bf16(ah, bl, acc[ct], 0, 0, 0);
                acc[ct] = __builtin_amdgcn_mfma_f32_16x16x32_bf16(al, bh, acc[ct], 0, 0, 0);
            }
        }
    }

    __syncthreads();
    #pragma unroll
    for (int ct = 0; ct < 4; ct++) {
        float b = bias[n0 + ct * 16 + c];
        #pragma unroll
        for (int r = 0; r < 4; r++)
            sout[(tb + g * 4 + r) * 68 + ct * 16 + c] = acc[ct][r] + b;
    }
    __syncthreads();
    #pragma unroll
    for (int r = 0; r < 4; r++) {
        int lin = tid + 256 * r;
        int row = lin >> 4, c4 = lin & 15;
        float4 v = *(const float4*)&sout[row * 68 + c4 * 4];
        *(float4*)&outp[(size_t)(m0 + row) * 256 + n0 + c4 * 4] = v;
    }
}

// ---------------------------------------------------------------------------
// MFMA flash attention, QT=128, with T14 async-STAGE split:
//   prologue: direct-stage tile 0 (K,V + 192-row P window), barrier,
//             issue tile-1 loads into regs.
//   loop kt:  compute(kt)  [tile kt+1 loads in flight under compute]
//             barrier; write regs->LDS (tile kt+1); barrier;
//             issue loads for tile kt+2.
// vmcnt drain for the staged loads lands one full compute-phase after issue.
// Circular 256-row P window: stage slots [relb+192,+256) are disjoint from
// read set [relb,+192) mod 256. All prefetch sources clamped (<= Pc-1).
// q and dpw pre-scaled by 1/8. LDS 133.3 KB -> 1 block (8 waves)/CU.
// ---------------------------------------------------------------------------
#define NTILES (Tc / 64)

__global__ __launch_bounds__(512) void attn_mfma(
    const unsigned short* __restrict__ qu,   // (B,H,T,DK) bf16, = (q+pbu)/8
    const unsigned short* __restrict__ kh,   // (B,H,T,DK) bf16
    const unsigned short* __restrict__ vh,   // (B,H,T,DK) bf16
    const unsigned short* __restrict__ ph,   // (H,P,DK)  bf16
    const float* __restrict__ dpw_g,         // (H,P), pre-scaled by 1/8
    const int*   __restrict__ mask,          // (B,T)
    unsigned short* __restrict__ xhi,        // (B,T,D) bf16 hi
    unsigned short* __restrict__ xlo)        // (B,T,D) bf16 lo
{
    __shared__ unsigned short sq[128 * 72];   // 18.4 KB
    __shared__ unsigned short sk[64 * 72];    //  9.2 KB
    __shared__ unsigned short svt[64 * 72];   //  9.2 KB  [dk][t^swz]
    __shared__ unsigned short sp[128 * 72];   // 18.4 KB  probs, wave-private rows
    __shared__ unsigned short spw[256 * 72];  // 36.9 KB  circular: phys = abs & 255
    __shared__ float sbdw[8][16 * 84];        // 43.0 KB  wave-private BD stripes
    __shared__ float sdpw[256];               // circular
    __shared__ float smask[64];

    const int tid = threadIdx.x;
    const int wv = tid >> 6;
    const int lane = tid & 63;
    const int c = lane & 15, g = lane >> 4;
    const int bh = blockIdx.x, b = bh >> 2, h = bh & 3;
    const int t0 = blockIdx.y * 128;
    const int tb = wv * 16;
    const int base0 = Tc - 128 - t0;          // window base at kt=0, >= 0

    const unsigned short* qbase = qu + ((size_t)bh * Tc + t0) * DKc;
    const unsigned short* kbase = kh + (size_t)bh * Tc * DKc;
    const unsigned short* vbase = vh + (size_t)bh * Tc * DKc;
    const unsigned short* pbase = ph + (size_t)h * Pc * DKc;

    const int srow = tid >> 3, sch = tid & 7;   // [0,64) x [0,8)

    // ---- Prologue: Q tile (128 rows) + full initial P window (192 rows)
    #pragma unroll
    for (int r = 0; r < 2; r++) {
        int lin = tid + 512 * r;
        int row = lin >> 3, ch = lin & 7;
        *(uint4*)&sq[row * 72 + ch * 8] =
            *(const uint4*)(qbase + (size_t)row * DKc + ch * 8);
    }
    #pragma unroll
    for (int r = 0; r < 3; r++) {
        int lin = tid + 512 * r;
        int row = lin >> 3, ch = lin & 7;     // row in [0,192)
        int a0 = base0 + row;                  // <= 1920+191 = 2111, in range
        *(uint4*)&spw[(a0 & 255) * 72 + ch * 8] =
            *(const uint4*)(pbase + (size_t)a0 * DKc + ch * 8);
    }
    if (tid < 192) sdpw[(base0 + tid) & 255] = dpw_g[h * Pc + base0 + tid];
    // K/V tile 0 direct
    *(uint4*)&sk[srow * 72 + sch * 8] =
        *(const uint4*)(kbase + (size_t)srow * DKc + sch * 8);
    {
        uint4 raw = *(const uint4*)(vbase + (size_t)srow * DKc + sch * 8);
        unsigned short el[8];
        __builtin_memcpy(el, &raw, 16);
        #pragma unroll
        for (int e = 0; e < 8; e++) {
            int dk = sch * 8 + e;
            svt[dk * 72 + (srow ^ ((dk >> 3) << 3))] = el[e];
        }
    }
    if (tid < 64) smask[tid] = (mask[b * Tc + tid] == 0) ? -1e9f : 0.f;
    __syncthreads();

    // ---- issue tile-1 loads into regs
    uint4 kreg, vreg, preg;
    float dpwreg = 0.f; int mreg = 1;
    {
        kreg = *(const uint4*)(kbase + (size_t)(64 + srow) * DKc + sch * 8);
        vreg = *(const uint4*)(vbase + (size_t)(64 + srow) * DKc + sch * 8);
        int pabs = base0 + 64 + 128 + srow;              // <= 2175, in range
        preg = *(const uint4*)(pbase + (size_t)pabs * DKc + sch * 8);
        if (tid < 64) {
            dpwreg = dpw_g[h * Pc + pabs - srow + tid];  // same base row range
            mreg = mask[b * Tc + 64 + tid];
        }
    }

    f32x4 O[4];
    #pragma unroll
    for (int ct = 0; ct < 4; ct++) O[ct] = (f32x4){0.f, 0.f, 0.f, 0.f};
    float mrow[4], lrow[4];
    #pragma unroll
    for (int r = 0; r < 4; r++) { mrow[r] = -3.0e38f; lrow[r] = 0.f; }

    bf16x8 qf0, qf1;
    qf0 = *(const bf16x8*)&sq[(tb + c) * 72 + g * 8];
    qf1 = *(const bf16x8*)&sq[(tb + c) * 72 + (4 + g) * 8];

    for (int kt = 0; kt < NTILES; kt++) {
        const int relb = base0 + kt * 64;

        __builtin_amdgcn_s_setprio(1);
        // ---- AC: 16x64 score stripe
        f32x4 sac[4];
        #pragma unroll
        for (int ct = 0; ct < 4; ct++) {
            f32x4 acc = (f32x4){0.f, 0.f, 0.f, 0.f};
            bf16x8 kf0 = *(const bf16x8*)&sk[(ct * 16 + c) * 72 + g * 8];
            bf16x8 kf1 = *(const bf16x8*)&sk[(ct * 16 + c) * 72 + (4 + g) * 8];
            acc = __builtin_amdgcn_mfma_f32_16x16x32_bf16(qf0, kf0, acc, 0, 0, 0);
            acc = __builtin_amdgcn_mfma_f32_16x16x32_bf16(qf1, kf1, acc, 0, 0, 0);
            sac[ct] = acc;
        }

        // ---- BD: 16x80 banded stripe -> wave-private LDS (+dpw folded)
        const int wstart = 112 - tb;
        #pragma unroll
        for (int wt = 0; wt < 5; wt++) {
            f32x4 acc = (f32x4){0.f, 0.f, 0.f, 0.f};
            int plog = wstart + wt * 16 + c;          // [0, 191]
            int phys = (relb + plog) & 255;
            bf16x8 pf0 = *(const bf16x8*)&spw[phys * 72 + g * 8];
            bf16x8 pf1 = *(const bf16x8*)&spw[phys * 72 + (4 + g) * 8];
            acc = __builtin_amdgcn_mfma_f32_16x16x32_bf16(qf0, pf0, acc, 0, 0, 0);
            acc = __builtin_amdgcn_mfma_f32_16x16x32_bf16(qf1, pf1, acc, 0, 0, 0);
            float dpwv = sdpw[phys];
            #pragma unroll
            for (int r = 0; r < 4; r++)
                sbdw[wv][(g * 4 + r) * 84 + wt * 16 + c] = acc[r] + dpwv;
        }
        __builtin_amdgcn_s_setprio(0);

        // ---- assemble scores: s = AC + BD[t][j-t+15] + mask (pre-scaled)
        float sreg[4][4];
        #pragma unroll
        for (int ct = 0; ct < 4; ct++) {
            float madd = smask[ct * 16 + c];
            #pragma unroll
            for (int r = 0; r < 4; r++) {
                int tt = g * 4 + r;
                int x = ct * 16 + c - tt + 15;        // in [0,78]
                sreg[ct][r] = sac[ct][r] + sbdw[wv][tt * 84 + x] + madd;
            }
        }

        // ---- online softmax
        float tmax[4], tsum[4];
        #pragma unroll
        for (int r = 0; r < 4; r++)
            tmax[r] = fmaxf(fmaxf(sreg[0][r], sreg[1][r]), fmaxf(sreg[2][r], sreg[3][r]));
        #pragma unroll
        for (int off = 1; off < 16; off <<= 1)
            #pragma unroll
            for (int r = 0; r < 4; r++)
                tmax[r] = fmaxf(tmax[r], __shfl_xor(tmax[r], off));

        float mnew[4], scl[4];
        #pragma unroll
        for (int r = 0; r < 4; r++) {
            mnew[r] = fmaxf(mrow[r], tmax[r]);
            scl[r] = __expf(mrow[r] - mnew[r]);
        }
        float pr[4][4];
        #pragma unroll
        for (int r = 0; r < 4; r++) {
            #pragma unroll
            for (int ct = 0; ct < 4; ct++)
                pr[ct][r] = __expf(sreg[ct][r] - mnew[r]);
            tsum[r] = (pr[0][r] + pr[1][r]) + (pr[2][r] + pr[3][r]);
        }
        #pragma unroll
        for (int off = 1; off < 16; off <<= 1)
            #pragma unroll
            for (int r = 0; r < 4; r++)
                tsum[r] += __shfl_xor(tsum[r], off);
        #pragma unroll
        for (int r = 0; r < 4; r++) {
            lrow[r] = lrow[r] * scl[r] + tsum[r];
            mrow[r] = mnew[r];
        }
        #pragma unroll
        for (int ct = 0; ct < 4; ct++) {
            f32x4 o = O[ct];
            o[0] *= scl[0]; o[1] *= scl[1]; o[2] *= scl[2]; o[3] *= scl[3];
            O[ct] = o;
        }

        // ---- P -> bf16 LDS (wave-private rows), then PV
        #pragma unroll
        for (int ct = 0; ct < 4; ct++)
            #pragma unroll
            for (int r = 0; r < 4; r++)
                sp[(tb + g * 4 + r) * 72 + ct * 16 + c] = f2bs(pr[ct][r]);

        __builtin_amdgcn_s_setprio(1);
        #pragma unroll
        for (int js = 0; js < 2; js++) {
            bf16x8 pfrag = *(const bf16x8*)&sp[(tb + c) * 72 + (js * 4 + g) * 8];
            #pragma unroll
            for (int ct = 0; ct < 4; ct++) {
                int dk = ct * 16 + c;
                int tcol = (js * 32 + g * 8) ^ ((dk >> 3) << 3);
                bf16x8 vf = *(const bf16x8*)&svt[dk * 72 + tcol];
                O[ct] = __builtin_amdgcn_mfma_f32_16x16x32_bf16(pfrag, vf, O[ct], 0, 0, 0);
            }
        }
        __builtin_amdgcn_s_setprio(0);

        if (kt == NTILES - 1) break;

        // ---- staging phase for tile kt+1 (regs were issued one phase ago)
        __syncthreads();                       // all waves done reading kt's LDS
        *(uint4*)&sk[srow * 72 + sch * 8] = kreg;
        {
            unsigned short el[8];
            __builtin_memcpy(el, &vreg, 16);
            #pragma unroll
            for (int e = 0; e < 8; e++) {
                int dk = sch * 8 + e;
                svt[dk * 72 + (srow ^ ((dk >> 3) << 3))] = el[e];
            }
        }
        {
            int pabs = relb + 64 + 128 + srow;             // slot for tile kt+1
            *(uint4*)&spw[(pabs & 255) * 72 + sch * 8] = preg;
        }
        if (tid < 64) {
            int da = relb + 64 + 128 + tid;
            sdpw[da & 255] = dpwreg;
            smask[tid] = (mreg == 0) ? -1e9f : 0.f;
        }
        __syncthreads();                       // tile kt+1 LDS ready

        // ---- issue loads for tile kt+2 (fly under next compute phase)
        if (kt + 2 < NTILES) {
            const int j0n = (kt + 2) * 64;
            kreg = *(const uint4*)(kbase + (size_t)(j0n + srow) * DKc + sch * 8);
            vreg = *(const uint4*)(vbase + (size_t)(j0n + srow) * DKc + sch * 8);
            int pabs = base0 + j0n + 128 + srow;
            int psrc = pabs <= Pc - 1 ? pabs : Pc - 1;     // clamp (hits 4095 at edge)
            preg = *(const uint4*)(pbase + (size_t)psrc * DKc + sch * 8);
            if (tid < 64) {
                int da = base0 + j0n + 128 + tid;
                dpwreg = dpw_g[h * Pc + (da <= Pc - 1 ? da : Pc - 1)];
                mreg = mask[b * Tc + j0n + tid];
            }
        }
    }

    // ---- epilogue: normalize, write bf16 hi + lo residual
    float invl[4];
    #pragma unroll
    for (int r = 0; r < 4; r++)
        invl[r] = (lrow[r] > 0.f) ? 1.f / lrow[r] : 0.f;
    #pragma unroll
    for (int ct = 0; ct < 4; ct++)
        #pragma unroll
        for (int r = 0; r < 4; r++) {
            size_t idx = ((size_t)(b * Tc + t0 + tb + g * 4 + r)) * Dc + h * DKc + ct * 16 + c;
            float v = O[ct][r] * invl[r];
            unsigned short hi = f2bs(v);
            xhi[idx] = hi;
            xlo[idx] = f2bs(v - bs2f(hi));
        }
}

// ---------------------------------------------------------------------------
extern "C" void kernel_launch(void* const* d_in, const int* in_sizes, int n_in,
                              void* d_out, int out_size, void* d_ws, size_t ws_size,
                              hipStream_t stream) {
    const float* query   = (const float*)d_in[0];
    const float* key_    = (const float*)d_in[1];
    const float* value   = (const float*)d_in[2];
    const float* pos_emb = (const float*)d_in[3];
    const int*   mask    = (const int*)d_in[4];
    const float* Wq  = (const float*)d_in[5];
    const float* bq  = (const float*)d_in[6];
    const float* Wk  = (const float*)d_in[7];
    const float* bk  = (const float*)d_in[8];
    const float* Wv  = (const float*)d_in[9];
    const float* bv  = (const float*)d_in[10];
    const float* Wpos = (const float*)d_in[11];
    const float* pbu = (const float*)d_in[12];
    const float* pbv = (const float*)d_in[13];
    const float* Wo  = (const float*)d_in[14];
    const float* bo  = (const float*)d_in[15];
    float* out = (float*)d_out;

    // Workspace layout (~22 MB)
    const size_t NQ = (size_t)Bc * Hc * Tc * DKc;       // 2,097,152
    unsigned short* qu_b = (unsigned short*)d_ws;
    unsigned short* kh_b = qu_b + NQ;
    unsigned short* vh_b = kh_b + NQ;
    unsigned short* ph_b = vh_b + NQ;                   // 1,048,576 slot
    unsigned short* xhi  = ph_b + 1048576;
    unsigned short* xlo  = xhi + NQ;
    float* dpw = (float*)(xlo + NQ);                    // 16,380 floats

    gemm_qkv<<<dim3(128, 4, 3), dim3(256), 0, stream>>>(query, key_, value,
        Wq, bq, Wk, bk, Wv, bv, pbu, qu_b, kh_b, vh_b);
    gemm_p<<<dim3(64, 4), dim3(256), 0, stream>>>(pos_emb, Wpos, pbu, pbv, ph_b, dpw);
    attn_mfma<<<dim3(Bc * Hc, Tc / 128), dim3(512), 0, stream>>>(
        qu_b, kh_b, vh_b, ph_b, dpw, mask, xhi, xlo);
    gemm_out_split<<<dim3(128, 4), dim3(256), 0, stream>>>(xhi, xlo, Wo, bo, out, Bc * Tc);
}